// Round 12
// baseline (443.944 us; speedup 1.0000x reference)
//
#include <hip/hip_runtime.h>
#include <hip/hip_bf16.h>
#include <stdint.h>

// ---------------------------------------------------------------------------
// SAM encoder attention, MI355X/gfx950.
// convert(fp32->bf16, q pre-scaled by scale*log2e) -> qkv_gemm (r10 version)
// -> rel_kernel -> flash v3.0 SPLIT-K (2 blocks per (n,qt), 2048 keys each;
// K LDS-staged, V direct global->reg; fp32 partial o/l to scratch) ->
// combine_kernel -> proj_gemm (r10 version).
// MFMA 16x16x32 bf16; layouts per verified m89/m120 mappings:
//   A/B: m(n)=lane&15, k=quad*8+j ; C/D: col=lane&15, row=quad*4+reg.
// Lessons: K MUST stage through LDS (r6); barrier amortization works (r8);
// r9 FAILED (VGPR cap -> spills); r10 bias-fold worked; r11 GEMM dbuf
// neutral (reverted). KEY: flash was GRID-limited at 3 blocks/CU (768/256)
// -- occupancy never moved. Split-K doubles blocks; V-direct cuts LDS to
// 25.6KB so 5 blocks/CU fit (launch_bounds(256,5), cap 102 VGPR).
// ---------------------------------------------------------------------------

typedef unsigned short ushort_t;
typedef __attribute__((ext_vector_type(8))) __bf16 bf16x8;
typedef __attribute__((ext_vector_type(4))) float f32x4;

#define NHD 12
#define HD 64
#define CIN 768
#define HWP 4096
#define QPRE 0.18033688f   /* 0.125 * log2(e) */

#if __has_builtin(__builtin_amdgcn_exp2f)
#define EXP2(x) __builtin_amdgcn_exp2f(x)
#else
#define EXP2(x) exp2f(x)
#endif

__device__ __forceinline__ ushort_t f2bf(float f) {
  union { float f; unsigned u; } v; v.f = f;
  unsigned r = (v.u + 0x7fffu + ((v.u >> 16) & 1u)) >> 16;  // RNE
  return (ushort_t)r;
}
__device__ __forceinline__ unsigned packbf(float a, float b) {
  unsigned ua = (__float_as_uint(a) + 0x8000u) >> 16;
  unsigned ub = (__float_as_uint(b) + 0x8000u) & 0xffff0000u;
  return ua | ub;
}
// HW packed f32x2 -> bf16x2 (v_cvt_pk_bf16_f32 on gfx950), lo=a hi=b
__device__ __forceinline__ unsigned cvtpk(float a, float b) {
  __hip_bfloat162 h = __float22bfloat162_rn(float2{a, b});
  unsigned u; __builtin_memcpy(&u, &h, 4); return u;
}
__device__ __forceinline__ f32x4 mfma16(bf16x8 a, bf16x8 b, f32x4 c) {
  return __builtin_amdgcn_mfma_f32_16x16x32_bf16(a, b, c, 0, 0, 0);
}
// bf16x8 with word0=(x), word1=(y), words 2-3 = 0 (zero slots are 0*0 in MFMA)
__device__ __forceinline__ bf16x8 make8lo(unsigned x, unsigned y) {
  union { uint4 u; bf16x8 v; } t;
  t.u = make_uint4(x, y, 0u, 0u);
  return t.v;
}
__device__ __forceinline__ bf16x8 asbf8(uint4 u) {
  union { uint4 u; bf16x8 v; } t; t.u = u; return t.v;
}

// async global->LDS, 16B per lane. LDS dest = wave-uniform base + lane*16.
typedef const __attribute__((address_space(1))) unsigned int* gas_u32p;
typedef __attribute__((address_space(3))) unsigned int* las_u32p;
__device__ __forceinline__ void glds16(const ushort_t* g, ushort_t* l) {
  __builtin_amdgcn_global_load_lds((gas_u32p)g, (las_u32p)l, 16, 0, 0);
}

// ---------------------------------------------------------------------------
// fp32 -> bf16 conversions, vectorized (16B load / 8B store per lane).
// ---------------------------------------------------------------------------
__global__ void convert_kernel(const float* __restrict__ x,
                               const float* __restrict__ wq, const float* __restrict__ bq,
                               const float* __restrict__ wk, const float* __restrict__ bk,
                               const float* __restrict__ wv, const float* __restrict__ bv,
                               const float* __restrict__ rph, const float* __restrict__ rpw,
                               const float* __restrict__ pw,
                               ushort_t* __restrict__ x_bf, ushort_t* __restrict__ w_bf,
                               ushort_t* __restrict__ pw_bf, ushort_t* __restrict__ rph_bf,
                               ushort_t* __restrict__ rpw_bf, float* __restrict__ bias_all) {
  const int i = blockIdx.x * blockDim.x + threadIdx.x;
  const int stride = gridDim.x * blockDim.x;
  const int NX4 = (HWP * CIN) / 4;
  const int NW4 = (NHD * HD * CIN) / 4;
  const int NR4 = (127 * HD) / 4;
  for (int t = i; t < NX4; t += stride) {
    float4 a = ((const float4*)x)[t];
    uint2 o; o.x = packbf(a.x, a.y); o.y = packbf(a.z, a.w);
    ((uint2*)x_bf)[t] = o;
  }
  for (int t = i; t < NW4; t += stride) {
    float4 a = ((const float4*)wq)[t];
    float4 b = ((const float4*)wk)[t];
    float4 c = ((const float4*)wv)[t];
    float4 d = ((const float4*)pw)[t];
    uint2 o;
    o.x = packbf(a.x, a.y); o.y = packbf(a.z, a.w); ((uint2*)w_bf)[t] = o;
    o.x = packbf(b.x, b.y); o.y = packbf(b.z, b.w); ((uint2*)w_bf)[NW4 + t] = o;
    o.x = packbf(c.x, c.y); o.y = packbf(c.z, c.w); ((uint2*)w_bf)[2 * NW4 + t] = o;
    o.x = packbf(d.x, d.y); o.y = packbf(d.z, d.w); ((uint2*)pw_bf)[t] = o;
  }
  for (int t = i; t < NR4; t += stride) {
    float4 a = ((const float4*)rph)[t];
    float4 b = ((const float4*)rpw)[t];
    uint2 o;
    o.x = packbf(a.x, a.y); o.y = packbf(a.z, a.w); ((uint2*)rph_bf)[t] = o;
    o.x = packbf(b.x, b.y); o.y = packbf(b.z, b.w); ((uint2*)rpw_bf)[t] = o;
  }
  for (int t = i; t < NHD * HD; t += stride) {
    bias_all[t]        = bq[t];
    bias_all[768 + t]  = bk[t];
    bias_all[1536 + t] = bv[t];
  }
}

// ---------------------------------------------------------------------------
// QKV GEMM (r10): 512 threads, 8 waves 2x4 of 64x32 tiles, glds staging into
// XOR-swizzled [128][32] LDS. q pre-scaled by QPRE; v packed 8B to [n][d][p].
// ---------------------------------------------------------------------------
__global__ __launch_bounds__(512) void qkv_gemm(
    const ushort_t* __restrict__ x_bf, const ushort_t* __restrict__ w_bf,
    const float* __restrict__ bias_all,
    ushort_t* __restrict__ q_bf, ushort_t* __restrict__ k_bf, ushort_t* __restrict__ v_t) {
  __shared__ ushort_t As[128 * 32];
  __shared__ ushort_t Bs[128 * 32];
  const int m0 = blockIdx.x * 128, n0 = blockIdx.y * 128;
  const int tid = threadIdx.x;
  const int lane = tid & 63, wid = tid >> 6;
  const int l15 = lane & 15, quad = lane >> 4;
  const int wm = (wid & 1) * 64;
  const int wn = (wid >> 1) * 32;
  const int gr = lane >> 2;
  const int cl = (lane & 3) ^ ((lane >> 3) & 3);
  const int swz = quad ^ ((l15 >> 1) & 3);
  const int Ra = wid * 16;

  f32x4 acc[4][2];
#pragma unroll
  for (int a = 0; a < 4; a++)
#pragma unroll
    for (int b = 0; b < 2; b++) acc[a][b] = (f32x4){0.f, 0.f, 0.f, 0.f};

  for (int kt = 0; kt < 24; kt++) {
    __syncthreads();
    const size_t kofs = (size_t)kt * 32 + cl * 8;
    glds16(&x_bf[(size_t)(m0 + Ra + gr) * CIN + kofs], &As[Ra * 32]);
    glds16(&w_bf[(size_t)(n0 + Ra + gr) * CIN + kofs], &Bs[Ra * 32]);
    __syncthreads();
    bf16x8 af[4], bfr[2];
#pragma unroll
    for (int mb = 0; mb < 4; mb++)
      af[mb] = *reinterpret_cast<const bf16x8*>(&As[(wm + mb * 16 + l15) * 32 + swz * 8]);
#pragma unroll
    for (int nb = 0; nb < 2; nb++)
      bfr[nb] = *reinterpret_cast<const bf16x8*>(&Bs[(wn + nb * 16 + l15) * 32 + swz * 8]);
#pragma unroll
    for (int mb = 0; mb < 4; mb++)
#pragma unroll
      for (int nb = 0; nb < 2; nb++)
        acc[mb][nb] = mfma16(af[mb], bfr[nb], acc[mb][nb]);
  }

#pragma unroll
  for (int mb = 0; mb < 4; mb++) {
#pragma unroll
    for (int nb = 0; nb < 2; nb++) {
      const int colg = n0 + wn + nb * 16 + l15;
      const float bias = bias_all[colg];
      if (colg >= 1536) {
        const int j = colg - 1536;
        uint2 wv2;
        wv2.x = packbf(acc[mb][nb][0] + bias, acc[mb][nb][1] + bias);
        wv2.y = packbf(acc[mb][nb][2] + bias, acc[mb][nb][3] + bias);
        *(uint2*)&v_t[(size_t)j * HWP + m0 + wm + mb * 16 + quad * 4] = wv2;
      } else {
#pragma unroll
        for (int r = 0; r < 4; r++) {
          const int rowg = m0 + wm + mb * 16 + quad * 4 + r;
          const float val = acc[mb][nb][r] + bias;
          if (colg < 768) {
            q_bf[(((size_t)(colg >> 6)) * HWP + rowg) * HD + (colg & 63)] = f2bf(val * QPRE);
          } else {
            const int j = colg - 768;
            k_bf[(((size_t)(j >> 6)) * HWP + rowg) * HD + (j & 63)] = f2bf(val);
          }
        }
      }
    }
  }
}

// ---------------------------------------------------------------------------
// rel tables. mode 0 -> rel_hT[n][h][t][w]; mode 1 -> rel_w[n][p][w2].
// Outputs *8 => rel * log2(e)  (q_bf pre-scaled by QPRE).
// ---------------------------------------------------------------------------
__global__ __launch_bounds__(256) void rel_kernel(
    const ushort_t* __restrict__ q_bf, const ushort_t* __restrict__ rph_bf,
    const ushort_t* __restrict__ rpw_bf,
    ushort_t* __restrict__ rel_hT, ushort_t* __restrict__ rel_w) {
  const int mode = blockIdx.y;
  const ushort_t* __restrict__ rp_bf = mode ? rpw_bf : rph_bf;
  const int bx = blockIdx.x;
  const int n = bx >> 6, hw = bx & 63;
  const int tid = threadIdx.x;
  const int lane = tid & 63, wid = tid >> 6;
  const int l15 = lane & 15, quad = lane >> 4;

  __shared__ ushort_t Qs[64][72];
  __shared__ ushort_t Rs[64][72];

  const int r0 = tid >> 3, c8 = (tid & 7) * 8;
#pragma unroll
  for (int h = 0; h < 2; h++) {
    const int r = r0 + h * 32;
    const int p = (mode == 0) ? (hw * 64 + r) : (r * 64 + hw);
    *(uint4*)&Qs[r][c8] = *(const uint4*)&q_bf[((size_t)n * HWP + p) * HD + c8];
    *(uint4*)&Rs[r][c8] = *(const uint4*)&rp_bf[(63 + hw - r) * HD + c8];
  }
  __syncthreads();

  bf16x8 a0 = *reinterpret_cast<const bf16x8*>(&Qs[wid * 16 + l15][quad * 8]);
  bf16x8 a1 = *reinterpret_cast<const bf16x8*>(&Qs[wid * 16 + l15][32 + quad * 8]);
#pragma unroll
  for (int nb = 0; nb < 4; nb++) {
    bf16x8 b0 = *reinterpret_cast<const bf16x8*>(&Rs[nb * 16 + l15][quad * 8]);
    bf16x8 b1 = *reinterpret_cast<const bf16x8*>(&Rs[nb * 16 + l15][32 + quad * 8]);
    f32x4 c = (f32x4){0.f, 0.f, 0.f, 0.f};
    c = mfma16(a0, b0, c);
    c = mfma16(a1, b1, c);
    const int col = nb * 16 + l15;
    if (mode == 0) {
      uint2 o;
      o.x = packbf(c[0] * 8.0f, c[1] * 8.0f);
      o.y = packbf(c[2] * 8.0f, c[3] * 8.0f);
      *(uint2*)&rel_hT[(((size_t)(n * 64 + hw) * 64) + col) * 64 + wid * 16 + quad * 4] = o;
    } else {
#pragma unroll
      for (int r = 0; r < 4; r++) {
        const int lr = wid * 16 + quad * 4 + r;
        const int p2 = lr * 64 + hw;
        rel_w[((size_t)n * HWP + p2) * 64 + col] = f2bf(c[r] * 8.0f);
      }
    }
  }
}

// ---------------------------------------------------------------------------
// Flash attention v3.0 SPLIT-K. Block bx = (n*64+qt)*2 + ks; ks selects keys
// [ks*2048, +2048). 4 waves 2x2 (wq = q-half, wk2 = key-half); 128-key
// double-tile per barrier pair. K glds-staged into XOR-swizzled LDS; V read
// DIRECT global->reg (16x64B fully-used segments, issued at B1, consumed
// ~300cyc later). Bias folded into MFMA slot-pairing; no-max exp2 softmax.
// Unnormalized fp32 o + l written to scratch; combine_kernel finishes.
// LDS 25.6KB + VGPR<=102 -> 5 blocks/CU (20 waves) vs old grid-limit of 3.
// ---------------------------------------------------------------------------
__global__ __launch_bounds__(256, 5) void flash_kernel(
    const ushort_t* __restrict__ q_bf, const ushort_t* __restrict__ k_bf,
    const ushort_t* __restrict__ v_t, const ushort_t* __restrict__ rel_hT,
    const ushort_t* __restrict__ rel_w, float* __restrict__ Opart,
    float* __restrict__ Lpart) {
  const int bx = blockIdx.x;                   // (n*64+qt)*2 + ks
  const int n = bx >> 7, qt = (bx >> 1) & 63, ks = bx & 1;
  const int q0 = qt * 64;
  const int tid = threadIdx.x;
  const int lane = tid & 63, wid = tid >> 6;
  const int l15 = lane & 15, quad = lane >> 4;
  const int wq = wid & 1, wk2 = wid >> 1;

  // LDS: Ks0@0, Ks1@8192 ([64][64] bf16 each), PsF@16384 [64][72] (9216).
  // Total 25600 B. Epilogue overlay: Obuf@0 [64][36] f32 (9216), Lred@16384.
  __shared__ __align__(16) char smem[25600];
  ushort_t* Ks[2] = {(ushort_t*)smem, (ushort_t*)(smem + 8192)};
  ushort_t* PsF = (ushort_t*)(smem + 16384);
  float* Obuf = (float*)smem;
  float* Lred = (float*)(smem + 16384);

  const int r0 = tid >> 3, c8 = (tid & 7) * 8;
#pragma unroll
  for (int h = 0; h < 2; h++) {
    const int r = r0 + h * 32;
    *(uint4*)&PsF[r * 72 + c8] = *(const uint4*)&q_bf[((size_t)n * HWP + q0 + r) * HD + c8];
  }
  __syncthreads();

  bf16x8 qb[2][2];
#pragma unroll
  for (int b = 0; b < 2; b++)
#pragma unroll
    for (int s = 0; s < 2; s++)
      qb[b][s] = *reinterpret_cast<const bf16x8*>(&PsF[(wq * 32 + b * 16 + l15) * 72 + s * 32 + quad * 8]);
  // First Ps write happens after B1 of it=0, which orders it against these
  // qb reads across all waves (barrier semantics).

  const int gr8 = lane >> 3;
  const int cl8 = (lane & 7) ^ (gr8 & 7);      // swizzled src col group
  const int rsw = l15 & 7;                     // read-side swizzle key

  // stage key tiles ks*32 + 2*it2 (buf 0) and +1 (buf 1); K only.
  auto stageK = [&](int it2) {
#pragma unroll
    for (int u = 0; u < 2; u++) {
      const int tt = ks * 32 + 2 * it2 + u;
      const size_t kbase = ((size_t)n * HWP + (size_t)tt * 64 + gr8) * HD + cl8 * 8;
#pragma unroll
      for (int i = 0; i < 2; i++) {
        const int R0 = wid * 16 + i * 8;
        glds16(&k_bf[kbase + (size_t)R0 * HD], &Ks[u][R0 * 64]);
      }
    }
  };
  stageK(0);

  // rh/rw prefetch (u16 coalesced), bases offset by ks*32 tiles:
  const ushort_t* rhbase = rel_hT + (((size_t)n * 64 + qt) << 12) + ((size_t)ks << 11);
  const ushort_t* rwbase = rel_w + (((size_t)n * HWP + q0) << 6) + ((size_t)ks << 11);
  ushort_t rhreg[2][2], rwreg[2][2];
#pragma unroll
  for (int u = 0; u < 2; u++) {
#pragma unroll
    for (int b = 0; b < 2; b++) {
      rhreg[u][b] = rhbase[u * 64 + wq * 32 + b * 16 + l15];
      rwreg[u][b] = rwbase[u * 64 + wk2 * 32 + b * 16 + l15];
    }
  }

  f32x4 od[4][2];
#pragma unroll
  for (int dt = 0; dt < 4; dt++)
#pragma unroll
    for (int b = 0; b < 2; b++) od[dt][b] = (f32x4){0.f, 0.f, 0.f, 0.f};
  float l_lane[2] = {0.f, 0.f};

  const bool isq0 = (quad == 0);

  for (int it = 0; it < 16; it++) {
    __syncthreads();   // B1: K DMA(it) complete everywhere (vmcnt drained)

    // --- V fragments: direct global loads, both halves, issued early ---
    uint4 vfr[2][4];
#pragma unroll
    for (int u = 0; u < 2; u++) {
      const size_t vb = (size_t)(n * HD + l15) * HWP +
                        (size_t)(ks * 32 + 2 * it + u) * 64 + wk2 * 32 + quad * 8;
#pragma unroll
      for (int dt = 0; dt < 4; dt++)
        vfr[u][dt] = *(const uint4*)&v_t[vb + (size_t)dt * 16 * HWP];
    }

    // --- K fragment reads for BOTH halves (before B2) ---
    bf16x8 af[2][2][2];
#pragma unroll
    for (int u = 0; u < 2; u++)
#pragma unroll
      for (int a = 0; a < 2; a++)
#pragma unroll
        for (int s = 0; s < 2; s++)
          af[u][a][s] = *reinterpret_cast<const bf16x8*>(
              &Ks[u][(wk2 * 32 + a * 16 + l15) * 64 + ((s * 4 + quad) ^ rsw) * 8]);

    // --- bias MFMA operand words (A: {1.0, rw}; B: {rh, 1.0}; lanes q>0: 0) ---
    unsigned aw[2][2], bw[2][2];
#pragma unroll
    for (int u = 0; u < 2; u++)
#pragma unroll
      for (int i = 0; i < 2; i++) {
        aw[u][i] = isq0 ? (((unsigned)rwreg[u][i] << 16) | 0x3F80u) : 0u;
        bw[u][i] = isq0 ? (0x3F800000u | (unsigned)rhreg[u][i]) : 0u;
      }

    // ---------------- compute half 0 ----------------
    {
      f32x4 sT[2][2];
#pragma unroll
      for (int a = 0; a < 2; a++)
#pragma unroll
        for (int b = 0; b < 2; b++) sT[a][b] = (f32x4){0.f, 0.f, 0.f, 0.f};
#pragma unroll
      for (int s = 0; s < 2; s++) {
        sT[0][0] = mfma16(af[0][0][s], qb[0][s], sT[0][0]);
        sT[0][1] = mfma16(af[0][0][s], qb[1][s], sT[0][1]);
        sT[1][0] = mfma16(af[0][1][s], qb[0][s], sT[1][0]);
        sT[1][1] = mfma16(af[0][1][s], qb[1][s], sT[1][1]);
      }
#pragma unroll
      for (int a = 0; a < 2; a++)
#pragma unroll
        for (int b = 0; b < 2; b++)
          sT[a][b] = mfma16(make8lo(aw[0][a], 0u), make8lo(bw[0][b], 0u), sT[a][b]);
#pragma unroll
      for (int b = 0; b < 2; b++) {
#pragma unroll
        for (int a = 0; a < 2; a++) {
          float p0 = EXP2(sT[a][b][0]);
          float p1 = EXP2(sT[a][b][1]);
          float p2 = EXP2(sT[a][b][2]);
          float p3 = EXP2(sT[a][b][3]);
          l_lane[b] += (p0 + p1) + (p2 + p3);
          uint2 w2; w2.x = cvtpk(p0, p1); w2.y = cvtpk(p2, p3);
          *(uint2*)&PsF[(wq * 32 + b * 16 + l15) * 72 + wk2 * 32 + a * 16 + quad * 4] = w2;
        }
      }
      bf16x8 pf0 = *reinterpret_cast<const bf16x8*>(&PsF[(wq * 32 + l15) * 72 + wk2 * 32 + quad * 8]);
      bf16x8 pf1 = *reinterpret_cast<const bf16x8*>(&PsF[(wq * 32 + 16 + l15) * 72 + wk2 * 32 + quad * 8]);
#pragma unroll
      for (int dt = 0; dt < 4; dt++) {
        od[dt][0] = mfma16(asbf8(vfr[0][dt]), pf0, od[dt][0]);
        od[dt][1] = mfma16(asbf8(vfr[0][dt]), pf1, od[dt][1]);
      }
    }

    __syncthreads();   // B2: all Ks reads done
    if (it < 15) {
      stageK(it + 1);   // K-DMA overlaps half-1 compute
#pragma unroll
      for (int u = 0; u < 2; u++)
#pragma unroll
        for (int b = 0; b < 2; b++) {
          rhreg[u][b] = rhbase[(2 * it + 2 + u) * 64 + wq * 32 + b * 16 + l15];
          rwreg[u][b] = rwbase[(2 * it + 2 + u) * 64 + wk2 * 32 + b * 16 + l15];
        }
    }

    // ---------------- compute half 1 ----------------
    {
      f32x4 sT[2][2];
#pragma unroll
      for (int a = 0; a < 2; a++)
#pragma unroll
        for (int b = 0; b < 2; b++) sT[a][b] = (f32x4){0.f, 0.f, 0.f, 0.f};
#pragma unroll
      for (int s = 0; s < 2; s++) {
        sT[0][0] = mfma16(af[1][0][s], qb[0][s], sT[0][0]);
        sT[0][1] = mfma16(af[1][0][s], qb[1][s], sT[0][1]);
        sT[1][0] = mfma16(af[1][1][s], qb[0][s], sT[1][0]);
        sT[1][1] = mfma16(af[1][1][s], qb[1][s], sT[1][1]);
      }
#pragma unroll
      for (int a = 0; a < 2; a++)
#pragma unroll
        for (int b = 0; b < 2; b++)
          sT[a][b] = mfma16(make8lo(aw[1][a], 0u), make8lo(bw[1][b], 0u), sT[a][b]);
#pragma unroll
      for (int b = 0; b < 2; b++) {
#pragma unroll
        for (int a = 0; a < 2; a++) {
          float p0 = EXP2(sT[a][b][0]);
          float p1 = EXP2(sT[a][b][1]);
          float p2 = EXP2(sT[a][b][2]);
          float p3 = EXP2(sT[a][b][3]);
          l_lane[b] += (p0 + p1) + (p2 + p3);
          uint2 w2; w2.x = cvtpk(p0, p1); w2.y = cvtpk(p2, p3);
          *(uint2*)&PsF[(wq * 32 + b * 16 + l15) * 72 + wk2 * 32 + a * 16 + quad * 4] = w2;
        }
      }
      bf16x8 pf0 = *reinterpret_cast<const bf16x8*>(&PsF[(wq * 32 + l15) * 72 + wk2 * 32 + quad * 8]);
      bf16x8 pf1 = *reinterpret_cast<const bf16x8*>(&PsF[(wq * 32 + 16 + l15) * 72 + wk2 * 32 + quad * 8]);
#pragma unroll
      for (int dt = 0; dt < 4; dt++) {
        od[dt][0] = mfma16(asbf8(vfr[1][dt]), pf0, od[dt][0]);
        od[dt][1] = mfma16(asbf8(vfr[1][dt]), pf1, od[dt][1]);
      }
    }
  }

  // --- epilogue: l quad-reduce; wk2-sum via LDS; fp32 partials to scratch ---
#pragma unroll
  for (int b = 0; b < 2; b++) {
    l_lane[b] += __shfl_xor(l_lane[b], 16, 64);
    l_lane[b] += __shfl_xor(l_lane[b], 32, 64);
  }
  __syncthreads();   // all loop LDS reads done before overlay
  if (wk2 == 0 && lane < 16) {
#pragma unroll
    for (int b = 0; b < 2; b++) Lred[wq * 32 + b * 16 + lane] = l_lane[b];
  }
  __syncthreads();
  if (wk2 == 1 && lane < 16) {
#pragma unroll
    for (int b = 0; b < 2; b++) {
      const int qi = wq * 32 + b * 16 + lane;
      Lpart[(size_t)bx * 64 + qi] = Lred[qi] + l_lane[b];
    }
  }
  // o: two d-half chunks through Obuf [64][36] f32
#pragma unroll
  for (int c = 0; c < 2; c++) {
    __syncthreads();
    if (wk2 == 0) {
#pragma unroll
      for (int dh = 0; dh < 2; dh++)
#pragma unroll
        for (int b = 0; b < 2; b++)
          *(f32x4*)&Obuf[(wq * 32 + b * 16 + l15) * 36 + dh * 16 + quad * 4] = od[2 * c + dh][b];
    }
    __syncthreads();
    if (wk2 == 1) {
#pragma unroll
      for (int dh = 0; dh < 2; dh++)
#pragma unroll
        for (int b = 0; b < 2; b++) {
          const int qi = wq * 32 + b * 16 + l15;
          f32x4 s = *(const f32x4*)&Obuf[qi * 36 + dh * 16 + quad * 4];
          s += od[2 * c + dh][b];
          *(f32x4*)&Opart[(size_t)bx * 4096 + qi * 64 + (2 * c + dh) * 16 + quad * 4] = s;
        }
    }
  }
}

// ---------------------------------------------------------------------------
// Combine: out = (O[ks=0] + O[ks=1]) / (L0 + L1), bf16, coalesced stores.
// Grid 768 (one block per (n,qt)), 256 threads.
// ---------------------------------------------------------------------------
__global__ __launch_bounds__(256) void combine_kernel(
    const float* __restrict__ Opart, const float* __restrict__ Lpart,
    ushort_t* __restrict__ ao_bf) {
  const int g = blockIdx.x;                    // n*64+qt
  const int n = g >> 6, qt = g & 63;
  const int tid = threadIdx.x;
  const int q = tid >> 2, db = (tid & 3) * 16;
  const float l = Lpart[(size_t)(g * 2) * 64 + q] + Lpart[(size_t)(g * 2 + 1) * 64 + q];
  const float linv = 1.0f / l;
  const float* p0 = Opart + (size_t)(g * 2) * 4096 + q * 64 + db;
  const float* p1 = p0 + 4096;
  unsigned outd[8];
#pragma unroll
  for (int j = 0; j < 4; j++) {
    f32x4 a = *(const f32x4*)(p0 + j * 4);
    f32x4 b = *(const f32x4*)(p1 + j * 4);
    a += b;
    outd[2 * j]     = cvtpk(a[0] * linv, a[1] * linv);
    outd[2 * j + 1] = cvtpk(a[2] * linv, a[3] * linv);
  }
  uint4 s0 = make_uint4(outd[0], outd[1], outd[2], outd[3]);
  uint4 s1 = make_uint4(outd[4], outd[5], outd[6], outd[7]);
  *(uint4*)&ao_bf[(size_t)(qt * 64 + q) * 768 + n * 64 + db]     = s0;
  *(uint4*)&ao_bf[(size_t)(qt * 64 + q) * 768 + n * 64 + db + 8] = s1;
}

// ---------------------------------------------------------------------------
// Output projection (r10): 64x128 tiles -> grid 384. fp32 out.
// ---------------------------------------------------------------------------
__global__ __launch_bounds__(256) void proj_gemm(
    const ushort_t* __restrict__ ao_bf, const ushort_t* __restrict__ pw_bf,
    const float* __restrict__ pb, float* __restrict__ out) {
  __shared__ ushort_t As[64 * 32];
  __shared__ ushort_t Bs[128 * 32];
  const int m0 = blockIdx.x * 64, n0 = blockIdx.y * 128;
  const int tid = threadIdx.x;
  const int lane = tid & 63, wid = tid >> 6;
  const int l15 = lane & 15, quad = lane >> 4;
  const int wm = (wid & 1) * 32;
  const int wn = (wid >> 1) * 64;
  const int gr = lane >> 2;
  const int cl = (lane & 3) ^ ((lane >> 3) & 3);
  const int swz = quad ^ ((l15 >> 1) & 3);
  const int Ra = wid * 16;

  f32x4 acc[2][4];
#pragma unroll
  for (int a = 0; a < 2; a++)
#pragma unroll
    for (int b = 0; b < 4; b++) acc[a][b] = (f32x4){0.f, 0.f, 0.f, 0.f};

  for (int kt = 0; kt < 24; kt++) {
    __syncthreads();
    const size_t kofs = (size_t)kt * 32 + cl * 8;
    glds16(&ao_bf[(size_t)(m0 + Ra + gr) * CIN + kofs],      &As[Ra * 32]);
    glds16(&pw_bf[(size_t)(n0 + Ra + gr) * CIN + kofs],      &Bs[Ra * 32]);
    glds16(&pw_bf[(size_t)(n0 + 64 + Ra + gr) * CIN + kofs], &Bs[(64 + Ra) * 32]);
    __syncthreads();
    bf16x8 af[2], bfr[4];
#pragma unroll
    for (int mb = 0; mb < 2; mb++)
      af[mb] = *reinterpret_cast<const bf16x8*>(&As[(wm + mb * 16 + l15) * 32 + swz * 8]);
#pragma unroll
    for (int nb = 0; nb < 4; nb++)
      bfr[nb] = *reinterpret_cast<const bf16x8*>(&Bs[(wn + nb * 16 + l15) * 32 + swz * 8]);
#pragma unroll
    for (int mb = 0; mb < 2; mb++)
#pragma unroll
      for (int nb = 0; nb < 4; nb++)
        acc[mb][nb] = mfma16(af[mb], bfr[nb], acc[mb][nb]);
  }

#pragma unroll
  for (int mb = 0; mb < 2; mb++) {
#pragma unroll
    for (int nb = 0; nb < 4; nb++) {
      const int colg = n0 + wn + nb * 16 + l15;
      const float bias = pb[colg];
#pragma unroll
      for (int r = 0; r < 4; r++) {
        const int rowg = m0 + wm + mb * 16 + quad * 4 + r;
        out[(size_t)rowg * 768 + colg] = acc[mb][nb][r] + bias;
      }
    }
  }
}

// ---------------------------------------------------------------------------
extern "C" void kernel_launch(void* const* d_in, const int* in_sizes, int n_in,
                              void* d_out, int out_size, void* d_ws, size_t ws_size,
                              hipStream_t stream) {
  (void)in_sizes; (void)n_in; (void)out_size; (void)ws_size;
  const float* x   = (const float*)d_in[0];
  const float* wq  = (const float*)d_in[1];
  const float* bq  = (const float*)d_in[2];
  const float* wk  = (const float*)d_in[3];
  const float* bk  = (const float*)d_in[4];
  const float* wv  = (const float*)d_in[5];
  const float* bv  = (const float*)d_in[6];
  const float* rph = (const float*)d_in[7];
  const float* rpw = (const float*)d_in[8];
  const float* pw  = (const float*)d_in[9];
  const float* pb  = (const float*)d_in[10];
  float* out = (float*)d_out;

  char* ws = (char*)d_ws;
  size_t off = 0;
  auto alloc = [&](size_t bytes) -> char* {
    char* p = ws + off;
    off += (bytes + 255) & ~(size_t)255;
    return p;
  };
  ushort_t* x_bf   = (ushort_t*)alloc((size_t)HWP * CIN * 2);
  ushort_t* w_bf   = (ushort_t*)alloc((size_t)3 * NHD * HD * CIN * 2);
  ushort_t* pw_bf  = (ushort_t*)alloc((size_t)NHD * HD * CIN * 2);
  ushort_t* rph_bf = (ushort_t*)alloc((size_t)127 * HD * 2);
  ushort_t* rpw_bf = (ushort_t*)alloc((size_t)127 * HD * 2);
  float*    bias_all = (float*)alloc((size_t)3 * NHD * HD * 4);
  ushort_t* q_bf   = (ushort_t*)alloc((size_t)NHD * HWP * HD * 2);
  ushort_t* k_bf   = (ushort_t*)alloc((size_t)NHD * HWP * HD * 2);
  ushort_t* v_t    = (ushort_t*)alloc((size_t)NHD * HWP * HD * 2);
  ushort_t* rel_hT = (ushort_t*)alloc((size_t)NHD * HWP * 64 * 2);
  ushort_t* rel_w  = (ushort_t*)alloc((size_t)NHD * HWP * 64 * 2);
  ushort_t* ao_bf  = (ushort_t*)alloc((size_t)HWP * CIN * 2);
  float*    Opart  = (float*)alloc((size_t)1536 * 4096 * 4);   // 25.2 MB
  float*    Lpart  = (float*)alloc((size_t)1536 * 64 * 4);     // 393 KB

  convert_kernel<<<dim3(2048), dim3(256), 0, stream>>>(
      x, wq, bq, wk, bk, wv, bv, rph, rpw, pw,
      x_bf, w_bf, pw_bf, rph_bf, rpw_bf, bias_all);
  qkv_gemm<<<dim3(32, 18), dim3(512), 0, stream>>>(
      x_bf, w_bf, bias_all, q_bf, k_bf, v_t);
  rel_kernel<<<dim3(NHD * 64, 2), dim3(256), 0, stream>>>(
      q_bf, rph_bf, rpw_bf, rel_hT, rel_w);
  flash_kernel<<<dim3(NHD * 64 * 2), dim3(256), 0, stream>>>(
      q_bf, k_bf, v_t, rel_hT, rel_w, Opart, Lpart);
  combine_kernel<<<dim3(NHD * 64), dim3(256), 0, stream>>>(Opart, Lpart, ao_bf);
  proj_gemm<<<dim3(64, 6), dim3(256), 0, stream>>>(ao_bf, pw_bf, pb, out);
}

// Round 13
// 208.163 us; speedup vs baseline: 2.1327x; 2.1327x over previous
//
#include <hip/hip_runtime.h>
#include <hip/hip_bf16.h>
#include <stdint.h>

// ---------------------------------------------------------------------------
// SAM encoder attention, MI355X/gfx950.
// convert(fp32->bf16, q pre-scaled by scale*log2e) -> qkv_gemm (512-thr,
// glds staging, single-buffer) -> rel_kernel -> flash v2.3 (r10, measured
// 93.5 us) -> proj_gemm (64x64 tiles, grid 768 = 3.0 blocks/CU balanced).
// MFMA 16x16x32 bf16; layouts per verified m89/m120 mappings:
//   A/B: m(n)=lane&15, k=quad*8+j ; C/D: col=lane&15, row=quad*4+reg.
// Lessons: K/V MUST stage through LDS (r6: 298us). Barrier amortization
// works (r8: 107.6->98.7). Bias-fold into MFMA slot-pair works (r10:
// 98.7->93.5). NEVER force occupancy via launch_bounds min-waves: flash
// inner loop needs ~84+ VGPRs; r9 (256,4@512thr) and r12 (256,5) both
// collapsed to spills (WRITE 278/418 MB). GEMM dbuf neutral (r11).
// Flash is grid-limited at 3 blocks/CU; split-K/split-q paths all hit the
// VGPR wall or double staging traffic -> plateau accepted at ~93.5 us.
// ---------------------------------------------------------------------------

typedef unsigned short ushort_t;
typedef __attribute__((ext_vector_type(8))) __bf16 bf16x8;
typedef __attribute__((ext_vector_type(4))) float f32x4;

#define NHD 12
#define HD 64
#define CIN 768
#define HWP 4096
#define QPRE 0.18033688f   /* 0.125 * log2(e) */

#if __has_builtin(__builtin_amdgcn_exp2f)
#define EXP2(x) __builtin_amdgcn_exp2f(x)
#else
#define EXP2(x) exp2f(x)
#endif

__device__ __forceinline__ ushort_t f2bf(float f) {
  union { float f; unsigned u; } v; v.f = f;
  unsigned r = (v.u + 0x7fffu + ((v.u >> 16) & 1u)) >> 16;  // RNE
  return (ushort_t)r;
}
__device__ __forceinline__ unsigned packbf(float a, float b) {
  unsigned ua = (__float_as_uint(a) + 0x8000u) >> 16;
  unsigned ub = (__float_as_uint(b) + 0x8000u) & 0xffff0000u;
  return ua | ub;
}
// HW packed f32x2 -> bf16x2 (v_cvt_pk_bf16_f32 on gfx950), lo=a hi=b
__device__ __forceinline__ unsigned cvtpk(float a, float b) {
  __hip_bfloat162 h = __float22bfloat162_rn(float2{a, b});
  unsigned u; __builtin_memcpy(&u, &h, 4); return u;
}
__device__ __forceinline__ f32x4 mfma16(bf16x8 a, bf16x8 b, f32x4 c) {
  return __builtin_amdgcn_mfma_f32_16x16x32_bf16(a, b, c, 0, 0, 0);
}
// bf16x8 with word0=(x), word1=(y), words 2-3 = 0 (zero slots are 0*0 in MFMA)
__device__ __forceinline__ bf16x8 make8lo(unsigned x, unsigned y) {
  union { uint4 u; bf16x8 v; } t;
  t.u = make_uint4(x, y, 0u, 0u);
  return t.v;
}

// async global->LDS, 16B per lane. LDS dest = wave-uniform base + lane*16.
typedef const __attribute__((address_space(1))) unsigned int* gas_u32p;
typedef __attribute__((address_space(3))) unsigned int* las_u32p;
__device__ __forceinline__ void glds16(const ushort_t* g, ushort_t* l) {
  __builtin_amdgcn_global_load_lds((gas_u32p)g, (las_u32p)l, 16, 0, 0);
}

// ---------------------------------------------------------------------------
// fp32 -> bf16 conversions, vectorized (16B load / 8B store per lane).
// ---------------------------------------------------------------------------
__global__ void convert_kernel(const float* __restrict__ x,
                               const float* __restrict__ wq, const float* __restrict__ bq,
                               const float* __restrict__ wk, const float* __restrict__ bk,
                               const float* __restrict__ wv, const float* __restrict__ bv,
                               const float* __restrict__ rph, const float* __restrict__ rpw,
                               const float* __restrict__ pw,
                               ushort_t* __restrict__ x_bf, ushort_t* __restrict__ w_bf,
                               ushort_t* __restrict__ pw_bf, ushort_t* __restrict__ rph_bf,
                               ushort_t* __restrict__ rpw_bf, float* __restrict__ bias_all) {
  const int i = blockIdx.x * blockDim.x + threadIdx.x;
  const int stride = gridDim.x * blockDim.x;
  const int NX4 = (HWP * CIN) / 4;
  const int NW4 = (NHD * HD * CIN) / 4;
  const int NR4 = (127 * HD) / 4;
  for (int t = i; t < NX4; t += stride) {
    float4 a = ((const float4*)x)[t];
    uint2 o; o.x = packbf(a.x, a.y); o.y = packbf(a.z, a.w);
    ((uint2*)x_bf)[t] = o;
  }
  for (int t = i; t < NW4; t += stride) {
    float4 a = ((const float4*)wq)[t];
    float4 b = ((const float4*)wk)[t];
    float4 c = ((const float4*)wv)[t];
    float4 d = ((const float4*)pw)[t];
    uint2 o;
    o.x = packbf(a.x, a.y); o.y = packbf(a.z, a.w); ((uint2*)w_bf)[t] = o;
    o.x = packbf(b.x, b.y); o.y = packbf(b.z, b.w); ((uint2*)w_bf)[NW4 + t] = o;
    o.x = packbf(c.x, c.y); o.y = packbf(c.z, c.w); ((uint2*)w_bf)[2 * NW4 + t] = o;
    o.x = packbf(d.x, d.y); o.y = packbf(d.z, d.w); ((uint2*)pw_bf)[t] = o;
  }
  for (int t = i; t < NR4; t += stride) {
    float4 a = ((const float4*)rph)[t];
    float4 b = ((const float4*)rpw)[t];
    uint2 o;
    o.x = packbf(a.x, a.y); o.y = packbf(a.z, a.w); ((uint2*)rph_bf)[t] = o;
    o.x = packbf(b.x, b.y); o.y = packbf(b.z, b.w); ((uint2*)rpw_bf)[t] = o;
  }
  for (int t = i; t < NHD * HD; t += stride) {
    bias_all[t]        = bq[t];
    bias_all[768 + t]  = bk[t];
    bias_all[1536 + t] = bv[t];
  }
}

// ---------------------------------------------------------------------------
// QKV GEMM (r10): 512 threads, 8 waves 2x4 of 64x32 tiles, glds staging into
// XOR-swizzled [128][32] LDS. q pre-scaled by QPRE; v packed 8B to [n][d][p].
// ---------------------------------------------------------------------------
__global__ __launch_bounds__(512) void qkv_gemm(
    const ushort_t* __restrict__ x_bf, const ushort_t* __restrict__ w_bf,
    const float* __restrict__ bias_all,
    ushort_t* __restrict__ q_bf, ushort_t* __restrict__ k_bf, ushort_t* __restrict__ v_t) {
  __shared__ ushort_t As[128 * 32];
  __shared__ ushort_t Bs[128 * 32];
  const int m0 = blockIdx.x * 128, n0 = blockIdx.y * 128;
  const int tid = threadIdx.x;
  const int lane = tid & 63, wid = tid >> 6;
  const int l15 = lane & 15, quad = lane >> 4;
  const int wm = (wid & 1) * 64;
  const int wn = (wid >> 1) * 32;
  const int gr = lane >> 2;
  const int cl = (lane & 3) ^ ((lane >> 3) & 3);
  const int swz = quad ^ ((l15 >> 1) & 3);
  const int Ra = wid * 16;

  f32x4 acc[4][2];
#pragma unroll
  for (int a = 0; a < 4; a++)
#pragma unroll
    for (int b = 0; b < 2; b++) acc[a][b] = (f32x4){0.f, 0.f, 0.f, 0.f};

  for (int kt = 0; kt < 24; kt++) {
    __syncthreads();
    const size_t kofs = (size_t)kt * 32 + cl * 8;
    glds16(&x_bf[(size_t)(m0 + Ra + gr) * CIN + kofs], &As[Ra * 32]);
    glds16(&w_bf[(size_t)(n0 + Ra + gr) * CIN + kofs], &Bs[Ra * 32]);
    __syncthreads();
    bf16x8 af[4], bfr[2];
#pragma unroll
    for (int mb = 0; mb < 4; mb++)
      af[mb] = *reinterpret_cast<const bf16x8*>(&As[(wm + mb * 16 + l15) * 32 + swz * 8]);
#pragma unroll
    for (int nb = 0; nb < 2; nb++)
      bfr[nb] = *reinterpret_cast<const bf16x8*>(&Bs[(wn + nb * 16 + l15) * 32 + swz * 8]);
#pragma unroll
    for (int mb = 0; mb < 4; mb++)
#pragma unroll
      for (int nb = 0; nb < 2; nb++)
        acc[mb][nb] = mfma16(af[mb], bfr[nb], acc[mb][nb]);
  }

#pragma unroll
  for (int mb = 0; mb < 4; mb++) {
#pragma unroll
    for (int nb = 0; nb < 2; nb++) {
      const int colg = n0 + wn + nb * 16 + l15;
      const float bias = bias_all[colg];
      if (colg >= 1536) {
        const int j = colg - 1536;
        uint2 wv2;
        wv2.x = packbf(acc[mb][nb][0] + bias, acc[mb][nb][1] + bias);
        wv2.y = packbf(acc[mb][nb][2] + bias, acc[mb][nb][3] + bias);
        *(uint2*)&v_t[(size_t)j * HWP + m0 + wm + mb * 16 + quad * 4] = wv2;
      } else {
#pragma unroll
        for (int r = 0; r < 4; r++) {
          const int rowg = m0 + wm + mb * 16 + quad * 4 + r;
          const float val = acc[mb][nb][r] + bias;
          if (colg < 768) {
            q_bf[(((size_t)(colg >> 6)) * HWP + rowg) * HD + (colg & 63)] = f2bf(val * QPRE);
          } else {
            const int j = colg - 768;
            k_bf[(((size_t)(j >> 6)) * HWP + rowg) * HD + (j & 63)] = f2bf(val);
          }
        }
      }
    }
  }
}

// ---------------------------------------------------------------------------
// rel tables. mode 0 -> rel_hT[n][h][t][w]; mode 1 -> rel_w[n][p][w2].
// Outputs *8 => rel * log2(e)  (q_bf pre-scaled by QPRE).
// ---------------------------------------------------------------------------
__global__ __launch_bounds__(256) void rel_kernel(
    const ushort_t* __restrict__ q_bf, const ushort_t* __restrict__ rph_bf,
    const ushort_t* __restrict__ rpw_bf,
    ushort_t* __restrict__ rel_hT, ushort_t* __restrict__ rel_w) {
  const int mode = blockIdx.y;
  const ushort_t* __restrict__ rp_bf = mode ? rpw_bf : rph_bf;
  const int bx = blockIdx.x;
  const int n = bx >> 6, hw = bx & 63;
  const int tid = threadIdx.x;
  const int lane = tid & 63, wid = tid >> 6;
  const int l15 = lane & 15, quad = lane >> 4;

  __shared__ ushort_t Qs[64][72];
  __shared__ ushort_t Rs[64][72];

  const int r0 = tid >> 3, c8 = (tid & 7) * 8;
#pragma unroll
  for (int h = 0; h < 2; h++) {
    const int r = r0 + h * 32;
    const int p = (mode == 0) ? (hw * 64 + r) : (r * 64 + hw);
    *(uint4*)&Qs[r][c8] = *(const uint4*)&q_bf[((size_t)n * HWP + p) * HD + c8];
    *(uint4*)&Rs[r][c8] = *(const uint4*)&rp_bf[(63 + hw - r) * HD + c8];
  }
  __syncthreads();

  bf16x8 a0 = *reinterpret_cast<const bf16x8*>(&Qs[wid * 16 + l15][quad * 8]);
  bf16x8 a1 = *reinterpret_cast<const bf16x8*>(&Qs[wid * 16 + l15][32 + quad * 8]);
#pragma unroll
  for (int nb = 0; nb < 4; nb++) {
    bf16x8 b0 = *reinterpret_cast<const bf16x8*>(&Rs[nb * 16 + l15][quad * 8]);
    bf16x8 b1 = *reinterpret_cast<const bf16x8*>(&Rs[nb * 16 + l15][32 + quad * 8]);
    f32x4 c = (f32x4){0.f, 0.f, 0.f, 0.f};
    c = mfma16(a0, b0, c);
    c = mfma16(a1, b1, c);
    const int col = nb * 16 + l15;
    if (mode == 0) {
      uint2 o;
      o.x = packbf(c[0] * 8.0f, c[1] * 8.0f);
      o.y = packbf(c[2] * 8.0f, c[3] * 8.0f);
      *(uint2*)&rel_hT[(((size_t)(n * 64 + hw) * 64) + col) * 64 + wid * 16 + quad * 4] = o;
    } else {
#pragma unroll
      for (int r = 0; r < 4; r++) {
        const int lr = wid * 16 + quad * 4 + r;
        const int p2 = lr * 64 + hw;
        rel_w[((size_t)n * HWP + p2) * 64 + col] = f2bf(c[r] * 8.0f);
      }
    }
  }
}

// ---------------------------------------------------------------------------
// Flash attention v2.3 (r10, measured 93.5 us) — unchanged.
// Block = (head n, q-row qt); 4 waves 2x2 (wq, wk2); 128-key double-tile per
// barrier pair; glds K/V staging + XOR swizzle; bias folded into MFMA
// slot-pairing; rh/rw as prefetched u16 global loads; no-max exp2 softmax.
// ---------------------------------------------------------------------------
__global__ __launch_bounds__(256, 3) void flash_kernel(
    const ushort_t* __restrict__ q_bf, const ushort_t* __restrict__ k_bf,
    const ushort_t* __restrict__ v_t, const ushort_t* __restrict__ rel_hT,
    const ushort_t* __restrict__ rel_w, ushort_t* __restrict__ ao_bf) {
  const int bx = blockIdx.x;
  const int n = bx >> 6, qt = bx & 63;
  const int q0 = qt * 64;
  const int tid = threadIdx.x;
  const int lane = tid & 63, wid = tid >> 6;
  const int l15 = lane & 15, quad = lane >> 4;
  const int wq = wid & 1, wk2 = wid >> 1;

  // LDS: Ks0@0, Ks1@8192, Vt0@16384, Vt1@24576 (each [64][64] bf16 = 8KB),
  // Ps/Qs@32768 [64][72] (9216), Lbuf@41984 [2][64] f32 (512). Total 42496.
  // o_buf [2][64][66] f32 (33792) overlays [0,33792) in the epilogue.
  __shared__ __align__(16) char smem[42496];
  ushort_t* Ks[2] = {(ushort_t*)smem, (ushort_t*)(smem + 8192)};
  ushort_t* Vt[2] = {(ushort_t*)(smem + 16384), (ushort_t*)(smem + 24576)};
  ushort_t* PsF  = (ushort_t*)(smem + 32768);
  float* Lbuf  = (float*)(smem + 41984);
  float* o_buf = (float*)smem;

  const int r0 = tid >> 3, c8 = (tid & 7) * 8;
#pragma unroll
  for (int h = 0; h < 2; h++) {
    const int r = r0 + h * 32;
    *(uint4*)&PsF[r * 72 + c8] = *(const uint4*)&q_bf[((size_t)n * HWP + q0 + r) * HD + c8];
  }
  __syncthreads();

  bf16x8 qb[2][2];
#pragma unroll
  for (int b = 0; b < 2; b++)
#pragma unroll
    for (int s = 0; s < 2; s++)
      qb[b][s] = *reinterpret_cast<const bf16x8*>(&PsF[(wq * 32 + b * 16 + l15) * 72 + s * 32 + quad * 8]);
  // First Ps write happens after B1 of it=0, which orders it against these
  // qb reads across all waves (barrier semantics).

  const int gr8 = lane >> 3;
  const int cl8 = (lane & 7) ^ ((lane >> 3) & 7);  // swizzled src col group
  const int rsw = l15 & 7;                         // read-side swizzle key

  // stages key tiles 2*it2 (buf 0) and 2*it2+1 (buf 1)
  auto stageKV = [&](int it2) {
#pragma unroll
    for (int u = 0; u < 2; u++) {
      const int tt = 2 * it2 + u;
      const size_t kbase = ((size_t)n * HWP + (size_t)tt * 64 + gr8) * HD + cl8 * 8;
#pragma unroll
      for (int i = 0; i < 2; i++) {
        const int R0 = wid * 16 + i * 8;
        glds16(&k_bf[kbase + (size_t)R0 * HD], &Ks[u][R0 * 64]);
      }
      const size_t vbase = ((size_t)n * HD + gr8) * HWP + (size_t)tt * 64 + cl8 * 8;
#pragma unroll
      for (int i = 0; i < 2; i++) {
        const int R0 = wid * 16 + i * 8;
        glds16(&v_t[vbase + (size_t)R0 * HWP], &Vt[u][R0 * 64]);
      }
    }
  };

  stageKV(0);

  // rh (per-q) and rw (per-key) prefetch, u16, coalesced:
  const ushort_t* rhbase = rel_hT + (((size_t)n * 64 + qt) << 12);
  const ushort_t* rwbase = rel_w + (((size_t)n * HWP + q0) << 6);
  ushort_t rhreg[2][2], rwreg[2][2];
#pragma unroll
  for (int u = 0; u < 2; u++) {
#pragma unroll
    for (int b = 0; b < 2; b++) {
      rhreg[u][b] = rhbase[u * 64 + wq * 32 + b * 16 + l15];
      rwreg[u][b] = rwbase[u * 64 + wk2 * 32 + b * 16 + l15];
    }
  }

  f32x4 od[4][2];
#pragma unroll
  for (int dt = 0; dt < 4; dt++)
#pragma unroll
    for (int b = 0; b < 2; b++) od[dt][b] = (f32x4){0.f, 0.f, 0.f, 0.f};
  float l_lane[2] = {0.f, 0.f};

  const bool isq0 = (quad == 0);

  for (int it = 0; it < 32; it++) {
    __syncthreads();   // B1: DMA(it) complete everywhere (vmcnt drained)

    // --- fragment reads for BOTH halves (before B2) ---
    bf16x8 af[2][2][2], vf[2][4];
#pragma unroll
    for (int u = 0; u < 2; u++) {
#pragma unroll
      for (int a = 0; a < 2; a++)
#pragma unroll
        for (int s = 0; s < 2; s++)
          af[u][a][s] = *reinterpret_cast<const bf16x8*>(
              &Ks[u][(wk2 * 32 + a * 16 + l15) * 64 + ((s * 4 + quad) ^ rsw) * 8]);
#pragma unroll
      for (int dt = 0; dt < 4; dt++)
        vf[u][dt] = *reinterpret_cast<const bf16x8*>(
            &Vt[u][(dt * 16 + l15) * 64 + ((wk2 * 4 + quad) ^ rsw) * 8]);
    }

    // --- bias MFMA operand words (A: {1.0, rw}; B: {rh, 1.0}; lanes q>0: 0) ---
    unsigned aw[2][2], bw[2][2];
#pragma unroll
    for (int u = 0; u < 2; u++)
#pragma unroll
      for (int i = 0; i < 2; i++) {
        aw[u][i] = isq0 ? (((unsigned)rwreg[u][i] << 16) | 0x3F80u) : 0u;
        bw[u][i] = isq0 ? (0x3F800000u | (unsigned)rhreg[u][i]) : 0u;
      }

    // ---------------- compute half 0 (t = 2it) ----------------
    {
      f32x4 sT[2][2];
#pragma unroll
      for (int a = 0; a < 2; a++)
#pragma unroll
        for (int b = 0; b < 2; b++) sT[a][b] = (f32x4){0.f, 0.f, 0.f, 0.f};
#pragma unroll
      for (int s = 0; s < 2; s++) {
        sT[0][0] = mfma16(af[0][0][s], qb[0][s], sT[0][0]);
        sT[0][1] = mfma16(af[0][0][s], qb[1][s], sT[0][1]);
        sT[1][0] = mfma16(af[0][1][s], qb[0][s], sT[1][0]);
        sT[1][1] = mfma16(af[0][1][s], qb[1][s], sT[1][1]);
      }
#pragma unroll
      for (int a = 0; a < 2; a++)
#pragma unroll
        for (int b = 0; b < 2; b++)
          sT[a][b] = mfma16(make8lo(aw[0][a], 0u), make8lo(bw[0][b], 0u), sT[a][b]);
#pragma unroll
      for (int b = 0; b < 2; b++) {
#pragma unroll
        for (int a = 0; a < 2; a++) {
          float p0 = EXP2(sT[a][b][0]);
          float p1 = EXP2(sT[a][b][1]);
          float p2 = EXP2(sT[a][b][2]);
          float p3 = EXP2(sT[a][b][3]);
          l_lane[b] += (p0 + p1) + (p2 + p3);
          uint2 w2; w2.x = cvtpk(p0, p1); w2.y = cvtpk(p2, p3);
          *(uint2*)&PsF[(wq * 32 + b * 16 + l15) * 72 + wk2 * 32 + a * 16 + quad * 4] = w2;
        }
      }
      bf16x8 pf0 = *reinterpret_cast<const bf16x8*>(&PsF[(wq * 32 + l15) * 72 + wk2 * 32 + quad * 8]);
      bf16x8 pf1 = *reinterpret_cast<const bf16x8*>(&PsF[(wq * 32 + 16 + l15) * 72 + wk2 * 32 + quad * 8]);
#pragma unroll
      for (int dt = 0; dt < 4; dt++) {
        od[dt][0] = mfma16(vf[0][dt], pf0, od[dt][0]);
        od[dt][1] = mfma16(vf[0][dt], pf1, od[dt][1]);
      }
    }

    __syncthreads();   // B2: all Ks/Vt reads done
    if (it < 31) {
      stageKV(it + 1);   // DMA overlaps half-1 compute
#pragma unroll
      for (int u = 0; u < 2; u++)
#pragma unroll
        for (int b = 0; b < 2; b++) {
          rhreg[u][b] = rhbase[(2 * it + 2 + u) * 64 + wq * 32 + b * 16 + l15];
          rwreg[u][b] = rwbase[(2 * it + 2 + u) * 64 + wk2 * 32 + b * 16 + l15];
        }
    }

    // ---------------- compute half 1 (t = 2it+1) ----------------
    {
      f32x4 sT[2][2];
#pragma unroll
      for (int a = 0; a < 2; a++)
#pragma unroll
        for (int b = 0; b < 2; b++) sT[a][b] = (f32x4){0.f, 0.f, 0.f, 0.f};
#pragma unroll
      for (int s = 0; s < 2; s++) {
        sT[0][0] = mfma16(af[1][0][s], qb[0][s], sT[0][0]);
        sT[0][1] = mfma16(af[1][0][s], qb[1][s], sT[0][1]);
        sT[1][0] = mfma16(af[1][1][s], qb[0][s], sT[1][0]);
        sT[1][1] = mfma16(af[1][1][s], qb[1][s], sT[1][1]);
      }
#pragma unroll
      for (int a = 0; a < 2; a++)
#pragma unroll
        for (int b = 0; b < 2; b++)
          sT[a][b] = mfma16(make8lo(aw[1][a], 0u), make8lo(bw[1][b], 0u), sT[a][b]);
#pragma unroll
      for (int b = 0; b < 2; b++) {
#pragma unroll
        for (int a = 0; a < 2; a++) {
          float p0 = EXP2(sT[a][b][0]);
          float p1 = EXP2(sT[a][b][1]);
          float p2 = EXP2(sT[a][b][2]);
          float p3 = EXP2(sT[a][b][3]);
          l_lane[b] += (p0 + p1) + (p2 + p3);
          uint2 w2; w2.x = cvtpk(p0, p1); w2.y = cvtpk(p2, p3);
          *(uint2*)&PsF[(wq * 32 + b * 16 + l15) * 72 + wk2 * 32 + a * 16 + quad * 4] = w2;
        }
      }
      bf16x8 pf0 = *reinterpret_cast<const bf16x8*>(&PsF[(wq * 32 + l15) * 72 + wk2 * 32 + quad * 8]);
      bf16x8 pf1 = *reinterpret_cast<const bf16x8*>(&PsF[(wq * 32 + 16 + l15) * 72 + wk2 * 32 + quad * 8]);
#pragma unroll
      for (int dt = 0; dt < 4; dt++) {
        od[dt][0] = mfma16(vf[1][dt], pf0, od[dt][0]);
        od[dt][1] = mfma16(vf[1][dt], pf1, od[dt][1]);
      }
    }
  }

  // --- combine l across quads, then across wk2 via LDS ---
#pragma unroll
  for (int b = 0; b < 2; b++) {
    l_lane[b] += __shfl_xor(l_lane[b], 16, 64);
    l_lane[b] += __shfl_xor(l_lane[b], 32, 64);
  }
  __syncthreads();   // all waves done with Ks/Vt/Ps before overlay
  if (lane < 16) {
#pragma unroll
    for (int b = 0; b < 2; b++)
      Lbuf[wk2 * 64 + wq * 32 + b * 16 + lane] = l_lane[b];
  }
#pragma unroll
  for (int dt = 0; dt < 4; dt++)
#pragma unroll
    for (int b = 0; b < 2; b++)
#pragma unroll
      for (int r = 0; r < 4; r++)
        o_buf[wk2 * 64 * 66 + (dt * 16 + quad * 4 + r) * 66 + (wq * 32 + b * 16 + l15)] =
            od[dt][b][r];
  __syncthreads();

  // --- cooperative epilogue: o = (part0+part1)/l, coalesced bf16 stores ---
  {
    const int q = tid >> 2, db = (tid & 3) * 16;
    const float linv = 1.0f / (Lbuf[q] + Lbuf[64 + q]);
    unsigned outd[8];
#pragma unroll
    for (int j = 0; j < 8; j++) {
      const int d0 = db + 2 * j;
      const float v0 = (o_buf[d0 * 66 + q] + o_buf[64 * 66 + d0 * 66 + q]) * linv;
      const float v1 = (o_buf[(d0 + 1) * 66 + q] + o_buf[64 * 66 + (d0 + 1) * 66 + q]) * linv;
      outd[j] = (unsigned)f2bf(v0) | ((unsigned)f2bf(v1) << 16);
    }
    uint4 s0 = make_uint4(outd[0], outd[1], outd[2], outd[3]);
    uint4 s1 = make_uint4(outd[4], outd[5], outd[6], outd[7]);
    *(uint4*)&ao_bf[(size_t)(q0 + q) * 768 + n * 64 + db]     = s0;
    *(uint4*)&ao_bf[(size_t)(q0 + q) * 768 + n * 64 + db + 8] = s1;
  }
}

// ---------------------------------------------------------------------------
// Output projection: 64x64 tiles -> grid 64x12 = 768 = 3.0 blocks/CU exactly
// (r10's 64x128 grid 384 = 1.5/CU had 2x tail imbalance). W re-reads are
// L2-resident (1.2 MB). 4 waves 2x2 of 32x32 tiles. fp32 out.
// ---------------------------------------------------------------------------
__global__ __launch_bounds__(256) void proj_gemm(
    const ushort_t* __restrict__ ao_bf, const ushort_t* __restrict__ pw_bf,
    const float* __restrict__ pb, float* __restrict__ out) {
  __shared__ ushort_t As[64 * 32];
  __shared__ ushort_t Bs[64 * 32];
  const int m0 = blockIdx.x * 64, n0 = blockIdx.y * 64;
  const int tid = threadIdx.x;
  const int lane = tid & 63, wid = tid >> 6;
  const int l15 = lane & 15, quad = lane >> 4;
  const int wm = (wid & 1) * 32;
  const int wn = (wid >> 1) * 32;
  const int gr = lane >> 2;
  const int cl = (lane & 3) ^ ((lane >> 3) & 3);
  const int swz = quad ^ ((l15 >> 1) & 3);
  const int Ra = wid * 16;

  f32x4 acc[2][2];
#pragma unroll
  for (int a = 0; a < 2; a++)
#pragma unroll
    for (int b = 0; b < 2; b++) acc[a][b] = (f32x4){0.f, 0.f, 0.f, 0.f};

  for (int kt = 0; kt < 24; kt++) {
    __syncthreads();
    const size_t kofs = (size_t)kt * 32 + cl * 8;
    glds16(&ao_bf[(size_t)(m0 + Ra + gr) * CIN + kofs], &As[Ra * 32]);
    glds16(&pw_bf[(size_t)(n0 + Ra + gr) * CIN + kofs], &Bs[Ra * 32]);
    __syncthreads();
    bf16x8 af[2], bfr[2];
#pragma unroll
    for (int mb = 0; mb < 2; mb++)
      af[mb] = *reinterpret_cast<const bf16x8*>(&As[(wm + mb * 16 + l15) * 32 + swz * 8]);
#pragma unroll
    for (int nb = 0; nb < 2; nb++)
      bfr[nb] = *reinterpret_cast<const bf16x8*>(&Bs[(wn + nb * 16 + l15) * 32 + swz * 8]);
#pragma unroll
    for (int mb = 0; mb < 2; mb++)
#pragma unroll
      for (int nb = 0; nb < 2; nb++)
        acc[mb][nb] = mfma16(af[mb], bfr[nb], acc[mb][nb]);
  }

#pragma unroll
  for (int mb = 0; mb < 2; mb++) {
#pragma unroll
    for (int nb = 0; nb < 2; nb++) {
      const int colg = n0 + wn + nb * 16 + l15;
      const float bias = pb[colg];
#pragma unroll
      for (int r = 0; r < 4; r++) {
        const int rowg = m0 + wm + mb * 16 + quad * 4 + r;
        out[(size_t)rowg * 768 + colg] = acc[mb][nb][r] + bias;
      }
    }
  }
}

// ---------------------------------------------------------------------------
extern "C" void kernel_launch(void* const* d_in, const int* in_sizes, int n_in,
                              void* d_out, int out_size, void* d_ws, size_t ws_size,
                              hipStream_t stream) {
  (void)in_sizes; (void)n_in; (void)out_size; (void)ws_size;
  const float* x   = (const float*)d_in[0];
  const float* wq  = (const float*)d_in[1];
  const float* bq  = (const float*)d_in[2];
  const float* wk  = (const float*)d_in[3];
  const float* bk  = (const float*)d_in[4];
  const float* wv  = (const float*)d_in[5];
  const float* bv  = (const float*)d_in[6];
  const float* rph = (const float*)d_in[7];
  const float* rpw = (const float*)d_in[8];
  const float* pw  = (const float*)d_in[9];
  const float* pb  = (const float*)d_in[10];
  float* out = (float*)d_out;

  char* ws = (char*)d_ws;
  size_t off = 0;
  auto alloc = [&](size_t bytes) -> char* {
    char* p = ws + off;
    off += (bytes + 255) & ~(size_t)255;
    return p;
  };
  ushort_t* x_bf   = (ushort_t*)alloc((size_t)HWP * CIN * 2);
  ushort_t* w_bf   = (ushort_t*)alloc((size_t)3 * NHD * HD * CIN * 2);
  ushort_t* pw_bf  = (ushort_t*)alloc((size_t)NHD * HD * CIN * 2);
  ushort_t* rph_bf = (ushort_t*)alloc((size_t)127 * HD * 2);
  ushort_t* rpw_bf = (ushort_t*)alloc((size_t)127 * HD * 2);
  float*    bias_all = (float*)alloc((size_t)3 * NHD * HD * 4);
  ushort_t* q_bf   = (ushort_t*)alloc((size_t)NHD * HWP * HD * 2);
  ushort_t* k_bf   = (ushort_t*)alloc((size_t)NHD * HWP * HD * 2);
  ushort_t* v_t    = (ushort_t*)alloc((size_t)NHD * HWP * HD * 2);
  ushort_t* rel_hT = (ushort_t*)alloc((size_t)NHD * HWP * 64 * 2);
  ushort_t* rel_w  = (ushort_t*)alloc((size_t)NHD * HWP * 64 * 2);
  ushort_t* ao_bf  = (ushort_t*)alloc((size_t)HWP * CIN * 2);

  convert_kernel<<<dim3(2048), dim3(256), 0, stream>>>(
      x, wq, bq, wk, bk, wv, bv, rph, rpw, pw,
      x_bf, w_bf, pw_bf, rph_bf, rpw_bf, bias_all);
  qkv_gemm<<<dim3(32, 18), dim3(512), 0, stream>>>(
      x_bf, w_bf, bias_all, q_bf, k_bf, v_t);
  rel_kernel<<<dim3(NHD * 64, 2), dim3(256), 0, stream>>>(
      q_bf, rph_bf, rpw_bf, rel_hT, rel_w);
  flash_kernel<<<dim3(NHD * 64), dim3(256), 0, stream>>>(
      q_bf, k_bf, v_t, rel_hT, rel_w, ao_bf);
  proj_gemm<<<dim3(64, 12), dim3(256), 0, stream>>>(ao_bf, pw_bf, pb, out);
}

// Round 14
// 207.978 us; speedup vs baseline: 2.1346x; 1.0009x over previous
//
#include <hip/hip_runtime.h>
#include <hip/hip_bf16.h>
#include <stdint.h>

// ---------------------------------------------------------------------------
// SAM encoder attention, MI355X/gfx950.
// convert(fp32->bf16, q pre-scaled by scale*log2e) -> qkv_gemm (64x128 tile,
// BK=64, grid 1152 = 4.5/CU) -> rel_kernel -> flash v2.3 (r10/r13, measured
// 92.9 us) -> proj_gemm (64x64, BK=64, grid 768 = 3.0/CU).
// MFMA 16x16x32 bf16; layouts per verified m89/m120 mappings:
//   A/B: m(n)=lane&15, k=quad*8+j ; C/D: col=lane&15, row=quad*4+reg.
// Lessons: K/V MUST stage through LDS (r6: 298us). Barrier amortization
// works (r8: 107.6->98.7). Bias-fold into MFMA slot-pair works (r10:
// 98.7->93.5). NEVER force occupancy via launch_bounds min-waves (r9/r12:
// VGPR collapse -> 278/418MB spills). GEMM dbuf neutral (r11). Flash
// grid-limited at 3 blocks/CU; plateau accepted ~93 us. Flash LDS access
// patterns verified at bank floor (r13 audit) - conflict counter is floor
// accounting. This round: GEMM BK=64 (barriers halved) + qkv grid balance
// (576=2.25/CU 33% tail -> 1152=4.5/CU 11% tail).
// ---------------------------------------------------------------------------

typedef unsigned short ushort_t;
typedef __attribute__((ext_vector_type(8))) __bf16 bf16x8;
typedef __attribute__((ext_vector_type(4))) float f32x4;

#define NHD 12
#define HD 64
#define CIN 768
#define HWP 4096
#define QPRE 0.18033688f   /* 0.125 * log2(e) */

#if __has_builtin(__builtin_amdgcn_exp2f)
#define EXP2(x) __builtin_amdgcn_exp2f(x)
#else
#define EXP2(x) exp2f(x)
#endif

__device__ __forceinline__ ushort_t f2bf(float f) {
  union { float f; unsigned u; } v; v.f = f;
  unsigned r = (v.u + 0x7fffu + ((v.u >> 16) & 1u)) >> 16;  // RNE
  return (ushort_t)r;
}
__device__ __forceinline__ unsigned packbf(float a, float b) {
  unsigned ua = (__float_as_uint(a) + 0x8000u) >> 16;
  unsigned ub = (__float_as_uint(b) + 0x8000u) & 0xffff0000u;
  return ua | ub;
}
// HW packed f32x2 -> bf16x2 (v_cvt_pk_bf16_f32 on gfx950), lo=a hi=b
__device__ __forceinline__ unsigned cvtpk(float a, float b) {
  __hip_bfloat162 h = __float22bfloat162_rn(float2{a, b});
  unsigned u; __builtin_memcpy(&u, &h, 4); return u;
}
__device__ __forceinline__ f32x4 mfma16(bf16x8 a, bf16x8 b, f32x4 c) {
  return __builtin_amdgcn_mfma_f32_16x16x32_bf16(a, b, c, 0, 0, 0);
}
// bf16x8 with word0=(x), word1=(y), words 2-3 = 0 (zero slots are 0*0 in MFMA)
__device__ __forceinline__ bf16x8 make8lo(unsigned x, unsigned y) {
  union { uint4 u; bf16x8 v; } t;
  t.u = make_uint4(x, y, 0u, 0u);
  return t.v;
}

// async global->LDS, 16B per lane. LDS dest = wave-uniform base + lane*16.
typedef const __attribute__((address_space(1))) unsigned int* gas_u32p;
typedef __attribute__((address_space(3))) unsigned int* las_u32p;
__device__ __forceinline__ void glds16(const ushort_t* g, ushort_t* l) {
  __builtin_amdgcn_global_load_lds((gas_u32p)g, (las_u32p)l, 16, 0, 0);
}

// ---------------------------------------------------------------------------
// fp32 -> bf16 conversions, vectorized (16B load / 8B store per lane).
// ---------------------------------------------------------------------------
__global__ void convert_kernel(const float* __restrict__ x,
                               const float* __restrict__ wq, const float* __restrict__ bq,
                               const float* __restrict__ wk, const float* __restrict__ bk,
                               const float* __restrict__ wv, const float* __restrict__ bv,
                               const float* __restrict__ rph, const float* __restrict__ rpw,
                               const float* __restrict__ pw,
                               ushort_t* __restrict__ x_bf, ushort_t* __restrict__ w_bf,
                               ushort_t* __restrict__ pw_bf, ushort_t* __restrict__ rph_bf,
                               ushort_t* __restrict__ rpw_bf, float* __restrict__ bias_all) {
  const int i = blockIdx.x * blockDim.x + threadIdx.x;
  const int stride = gridDim.x * blockDim.x;
  const int NX4 = (HWP * CIN) / 4;
  const int NW4 = (NHD * HD * CIN) / 4;
  const int NR4 = (127 * HD) / 4;
  for (int t = i; t < NX4; t += stride) {
    float4 a = ((const float4*)x)[t];
    uint2 o; o.x = packbf(a.x, a.y); o.y = packbf(a.z, a.w);
    ((uint2*)x_bf)[t] = o;
  }
  for (int t = i; t < NW4; t += stride) {
    float4 a = ((const float4*)wq)[t];
    float4 b = ((const float4*)wk)[t];
    float4 c = ((const float4*)wv)[t];
    float4 d = ((const float4*)pw)[t];
    uint2 o;
    o.x = packbf(a.x, a.y); o.y = packbf(a.z, a.w); ((uint2*)w_bf)[t] = o;
    o.x = packbf(b.x, b.y); o.y = packbf(b.z, b.w); ((uint2*)w_bf)[NW4 + t] = o;
    o.x = packbf(c.x, c.y); o.y = packbf(c.z, c.w); ((uint2*)w_bf)[2 * NW4 + t] = o;
    o.x = packbf(d.x, d.y); o.y = packbf(d.z, d.w); ((uint2*)pw_bf)[t] = o;
  }
  for (int t = i; t < NR4; t += stride) {
    float4 a = ((const float4*)rph)[t];
    float4 b = ((const float4*)rpw)[t];
    uint2 o;
    o.x = packbf(a.x, a.y); o.y = packbf(a.z, a.w); ((uint2*)rph_bf)[t] = o;
    o.x = packbf(b.x, b.y); o.y = packbf(b.z, b.w); ((uint2*)rpw_bf)[t] = o;
  }
  for (int t = i; t < NHD * HD; t += stride) {
    bias_all[t]        = bq[t];
    bias_all[768 + t]  = bk[t];
    bias_all[1536 + t] = bv[t];
  }
}

// ---------------------------------------------------------------------------
// QKV GEMM: C(4096x2304) = X * W^T. 64x128 tile, 256 threads (4 waves 2x2 of
// 32x64), BK=64, grid (64,18)=1152 = 4.5 blocks/CU (11% tail vs 33% at 576).
// glds staging into XOR-chunk-swizzled [64][64]/[128][64] LDS (flash's
// verified pattern: LDS[r][c] = global[r][c^(r&7)], read chunk (g)^(row&7)).
// Barriers 24 (vs 48 at BK=32). q pre-scaled by QPRE; v packed 8B [n][d][p].
// ---------------------------------------------------------------------------
__global__ __launch_bounds__(256) void qkv_gemm(
    const ushort_t* __restrict__ x_bf, const ushort_t* __restrict__ w_bf,
    const float* __restrict__ bias_all,
    ushort_t* __restrict__ q_bf, ushort_t* __restrict__ k_bf, ushort_t* __restrict__ v_t) {
  __shared__ ushort_t As[64 * 64];    // 8 KB
  __shared__ ushort_t Bs[128 * 64];   // 16 KB
  const int m0 = blockIdx.x * 64, n0 = blockIdx.y * 128;
  const int tid = threadIdx.x;
  const int lane = tid & 63, wid = tid >> 6;
  const int l15 = lane & 15, quad = lane >> 4;
  const int wm = (wid & 1) * 32;                 // m-half (32 rows)
  const int wn = (wid >> 1) * 64;                // n-half (64 cols)
  const int gr8 = lane >> 3;                     // row within 8-row group
  const int cl8 = (lane & 7) ^ (gr8 & 7);        // swizzled source chunk
  const int rsw = l15 & 7;                       // read-side swizzle key

  f32x4 acc[2][4];
#pragma unroll
  for (int a = 0; a < 2; a++)
#pragma unroll
    for (int b = 0; b < 4; b++) acc[a][b] = (f32x4){0.f, 0.f, 0.f, 0.f};

  for (int kt = 0; kt < 12; kt++) {
    __syncthreads();   // prior-iter frag reads done before overwrite
    const size_t kofs = (size_t)kt * 64 + cl8 * 8;
    // A: 64 rows = 8 groups of 8; 2 per wave
    glds16(&x_bf[(size_t)(m0 + wid * 16 + gr8) * CIN + kofs],     &As[(wid * 16) * 64]);
    glds16(&x_bf[(size_t)(m0 + wid * 16 + 8 + gr8) * CIN + kofs], &As[(wid * 16 + 8) * 64]);
    // B: 128 rows = 16 groups; 4 per wave
    glds16(&w_bf[(size_t)(n0 + wid * 32 + gr8) * CIN + kofs],      &Bs[(wid * 32) * 64]);
    glds16(&w_bf[(size_t)(n0 + wid * 32 + 8 + gr8) * CIN + kofs],  &Bs[(wid * 32 + 8) * 64]);
    glds16(&w_bf[(size_t)(n0 + wid * 32 + 16 + gr8) * CIN + kofs], &Bs[(wid * 32 + 16) * 64]);
    glds16(&w_bf[(size_t)(n0 + wid * 32 + 24 + gr8) * CIN + kofs], &Bs[(wid * 32 + 24) * 64]);
    __syncthreads();   // DMA complete (vmcnt drained at barrier)
    bf16x8 af[2][2], bfr[4][2];
#pragma unroll
    for (int mb = 0; mb < 2; mb++)
#pragma unroll
      for (int s = 0; s < 2; s++)
        af[mb][s] = *reinterpret_cast<const bf16x8*>(
            &As[(wm + mb * 16 + l15) * 64 + (((s * 4 + quad) ^ rsw) * 8)]);
#pragma unroll
    for (int nb = 0; nb < 4; nb++)
#pragma unroll
      for (int s = 0; s < 2; s++)
        bfr[nb][s] = *reinterpret_cast<const bf16x8*>(
            &Bs[(wn + nb * 16 + l15) * 64 + (((s * 4 + quad) ^ rsw) * 8)]);
#pragma unroll
    for (int mb = 0; mb < 2; mb++)
#pragma unroll
      for (int nb = 0; nb < 4; nb++)
#pragma unroll
        for (int s = 0; s < 2; s++)
          acc[mb][nb] = mfma16(af[mb][s], bfr[nb][s], acc[mb][nb]);
  }

#pragma unroll
  for (int mb = 0; mb < 2; mb++) {
#pragma unroll
    for (int nb = 0; nb < 4; nb++) {
      const int colg = n0 + wn + nb * 16 + l15;
      const float bias = bias_all[colg];
      if (colg >= 1536) {
        const int j = colg - 1536;
        uint2 wv2;
        wv2.x = packbf(acc[mb][nb][0] + bias, acc[mb][nb][1] + bias);
        wv2.y = packbf(acc[mb][nb][2] + bias, acc[mb][nb][3] + bias);
        *(uint2*)&v_t[(size_t)j * HWP + m0 + wm + mb * 16 + quad * 4] = wv2;
      } else {
#pragma unroll
        for (int r = 0; r < 4; r++) {
          const int rowg = m0 + wm + mb * 16 + quad * 4 + r;
          const float val = acc[mb][nb][r] + bias;
          if (colg < 768) {
            q_bf[(((size_t)(colg >> 6)) * HWP + rowg) * HD + (colg & 63)] = f2bf(val * QPRE);
          } else {
            const int j = colg - 768;
            k_bf[(((size_t)(j >> 6)) * HWP + rowg) * HD + (j & 63)] = f2bf(val);
          }
        }
      }
    }
  }
}

// ---------------------------------------------------------------------------
// rel tables. mode 0 -> rel_hT[n][h][t][w]; mode 1 -> rel_w[n][p][w2].
// Outputs *8 => rel * log2(e)  (q_bf pre-scaled by QPRE).
// ---------------------------------------------------------------------------
__global__ __launch_bounds__(256) void rel_kernel(
    const ushort_t* __restrict__ q_bf, const ushort_t* __restrict__ rph_bf,
    const ushort_t* __restrict__ rpw_bf,
    ushort_t* __restrict__ rel_hT, ushort_t* __restrict__ rel_w) {
  const int mode = blockIdx.y;
  const ushort_t* __restrict__ rp_bf = mode ? rpw_bf : rph_bf;
  const int bx = blockIdx.x;
  const int n = bx >> 6, hw = bx & 63;
  const int tid = threadIdx.x;
  const int lane = tid & 63, wid = tid >> 6;
  const int l15 = lane & 15, quad = lane >> 4;

  __shared__ ushort_t Qs[64][72];
  __shared__ ushort_t Rs[64][72];

  const int r0 = tid >> 3, c8 = (tid & 7) * 8;
#pragma unroll
  for (int h = 0; h < 2; h++) {
    const int r = r0 + h * 32;
    const int p = (mode == 0) ? (hw * 64 + r) : (r * 64 + hw);
    *(uint4*)&Qs[r][c8] = *(const uint4*)&q_bf[((size_t)n * HWP + p) * HD + c8];
    *(uint4*)&Rs[r][c8] = *(const uint4*)&rp_bf[(63 + hw - r) * HD + c8];
  }
  __syncthreads();

  bf16x8 a0 = *reinterpret_cast<const bf16x8*>(&Qs[wid * 16 + l15][quad * 8]);
  bf16x8 a1 = *reinterpret_cast<const bf16x8*>(&Qs[wid * 16 + l15][32 + quad * 8]);
#pragma unroll
  for (int nb = 0; nb < 4; nb++) {
    bf16x8 b0 = *reinterpret_cast<const bf16x8*>(&Rs[nb * 16 + l15][quad * 8]);
    bf16x8 b1 = *reinterpret_cast<const bf16x8*>(&Rs[nb * 16 + l15][32 + quad * 8]);
    f32x4 c = (f32x4){0.f, 0.f, 0.f, 0.f};
    c = mfma16(a0, b0, c);
    c = mfma16(a1, b1, c);
    const int col = nb * 16 + l15;
    if (mode == 0) {
      uint2 o;
      o.x = packbf(c[0] * 8.0f, c[1] * 8.0f);
      o.y = packbf(c[2] * 8.0f, c[3] * 8.0f);
      *(uint2*)&rel_hT[(((size_t)(n * 64 + hw) * 64) + col) * 64 + wid * 16 + quad * 4] = o;
    } else {
#pragma unroll
      for (int r = 0; r < 4; r++) {
        const int lr = wid * 16 + quad * 4 + r;
        const int p2 = lr * 64 + hw;
        rel_w[((size_t)n * HWP + p2) * 64 + col] = f2bf(c[r] * 8.0f);
      }
    }
  }
}

// ---------------------------------------------------------------------------
// Flash attention v2.3 (r10/r13, measured 92.9 us) — unchanged.
// Block = (head n, q-row qt); 4 waves 2x2 (wq, wk2); 128-key double-tile per
// barrier pair; glds K/V staging + XOR swizzle; bias folded into MFMA
// slot-pairing; rh/rw as prefetched u16 global loads; no-max exp2 softmax.
// ---------------------------------------------------------------------------
__global__ __launch_bounds__(256, 3) void flash_kernel(
    const ushort_t* __restrict__ q_bf, const ushort_t* __restrict__ k_bf,
    const ushort_t* __restrict__ v_t, const ushort_t* __restrict__ rel_hT,
    const ushort_t* __restrict__ rel_w, ushort_t* __restrict__ ao_bf) {
  const int bx = blockIdx.x;
  const int n = bx >> 6, qt = bx & 63;
  const int q0 = qt * 64;
  const int tid = threadIdx.x;
  const int lane = tid & 63, wid = tid >> 6;
  const int l15 = lane & 15, quad = lane >> 4;
  const int wq = wid & 1, wk2 = wid >> 1;

  // LDS: Ks0@0, Ks1@8192, Vt0@16384, Vt1@24576 (each [64][64] bf16 = 8KB),
  // Ps/Qs@32768 [64][72] (9216), Lbuf@41984 [2][64] f32 (512). Total 42496.
  // o_buf [2][64][66] f32 (33792) overlays [0,33792) in the epilogue.
  __shared__ __align__(16) char smem[42496];
  ushort_t* Ks[2] = {(ushort_t*)smem, (ushort_t*)(smem + 8192)};
  ushort_t* Vt[2] = {(ushort_t*)(smem + 16384), (ushort_t*)(smem + 24576)};
  ushort_t* PsF  = (ushort_t*)(smem + 32768);
  float* Lbuf  = (float*)(smem + 41984);
  float* o_buf = (float*)smem;

  const int r0 = tid >> 3, c8 = (tid & 7) * 8;
#pragma unroll
  for (int h = 0; h < 2; h++) {
    const int r = r0 + h * 32;
    *(uint4*)&PsF[r * 72 + c8] = *(const uint4*)&q_bf[((size_t)n * HWP + q0 + r) * HD + c8];
  }
  __syncthreads();

  bf16x8 qb[2][2];
#pragma unroll
  for (int b = 0; b < 2; b++)
#pragma unroll
    for (int s = 0; s < 2; s++)
      qb[b][s] = *reinterpret_cast<const bf16x8*>(&PsF[(wq * 32 + b * 16 + l15) * 72 + s * 32 + quad * 8]);
  // First Ps write happens after B1 of it=0, which orders it against these
  // qb reads across all waves (barrier semantics).

  const int gr8 = lane >> 3;
  const int cl8 = (lane & 7) ^ ((lane >> 3) & 7);  // swizzled src col group
  const int rsw = l15 & 7;                         // read-side swizzle key

  // stages key tiles 2*it2 (buf 0) and 2*it2+1 (buf 1)
  auto stageKV = [&](int it2) {
#pragma unroll
    for (int u = 0; u < 2; u++) {
      const int tt = 2 * it2 + u;
      const size_t kbase = ((size_t)n * HWP + (size_t)tt * 64 + gr8) * HD + cl8 * 8;
#pragma unroll
      for (int i = 0; i < 2; i++) {
        const int R0 = wid * 16 + i * 8;
        glds16(&k_bf[kbase + (size_t)R0 * HD], &Ks[u][R0 * 64]);
      }
      const size_t vbase = ((size_t)n * HD + gr8) * HWP + (size_t)tt * 64 + cl8 * 8;
#pragma unroll
      for (int i = 0; i < 2; i++) {
        const int R0 = wid * 16 + i * 8;
        glds16(&v_t[vbase + (size_t)R0 * HWP], &Vt[u][R0 * 64]);
      }
    }
  };

  stageKV(0);

  // rh (per-q) and rw (per-key) prefetch, u16, coalesced:
  const ushort_t* rhbase = rel_hT + (((size_t)n * 64 + qt) << 12);
  const ushort_t* rwbase = rel_w + (((size_t)n * HWP + q0) << 6);
  ushort_t rhreg[2][2], rwreg[2][2];
#pragma unroll
  for (int u = 0; u < 2; u++) {
#pragma unroll
    for (int b = 0; b < 2; b++) {
      rhreg[u][b] = rhbase[u * 64 + wq * 32 + b * 16 + l15];
      rwreg[u][b] = rwbase[u * 64 + wk2 * 32 + b * 16 + l15];
    }
  }

  f32x4 od[4][2];
#pragma unroll
  for (int dt = 0; dt < 4; dt++)
#pragma unroll
    for (int b = 0; b < 2; b++) od[dt][b] = (f32x4){0.f, 0.f, 0.f, 0.f};
  float l_lane[2] = {0.f, 0.f};

  const bool isq0 = (quad == 0);

  for (int it = 0; it < 32; it++) {
    __syncthreads();   // B1: DMA(it) complete everywhere (vmcnt drained)

    // --- fragment reads for BOTH halves (before B2) ---
    bf16x8 af[2][2][2], vf[2][4];
#pragma unroll
    for (int u = 0; u < 2; u++) {
#pragma unroll
      for (int a = 0; a < 2; a++)
#pragma unroll
        for (int s = 0; s < 2; s++)
          af[u][a][s] = *reinterpret_cast<const bf16x8*>(
              &Ks[u][(wk2 * 32 + a * 16 + l15) * 64 + ((s * 4 + quad) ^ rsw) * 8]);
#pragma unroll
      for (int dt = 0; dt < 4; dt++)
        vf[u][dt] = *reinterpret_cast<const bf16x8*>(
            &Vt[u][(dt * 16 + l15) * 64 + ((wk2 * 4 + quad) ^ rsw) * 8]);
    }

    // --- bias MFMA operand words (A: {1.0, rw}; B: {rh, 1.0}; lanes q>0: 0) ---
    unsigned aw[2][2], bw[2][2];
#pragma unroll
    for (int u = 0; u < 2; u++)
#pragma unroll
      for (int i = 0; i < 2; i++) {
        aw[u][i] = isq0 ? (((unsigned)rwreg[u][i] << 16) | 0x3F80u) : 0u;
        bw[u][i] = isq0 ? (0x3F800000u | (unsigned)rhreg[u][i]) : 0u;
      }

    // ---------------- compute half 0 (t = 2it) ----------------
    {
      f32x4 sT[2][2];
#pragma unroll
      for (int a = 0; a < 2; a++)
#pragma unroll
        for (int b = 0; b < 2; b++) sT[a][b] = (f32x4){0.f, 0.f, 0.f, 0.f};
#pragma unroll
      for (int s = 0; s < 2; s++) {
        sT[0][0] = mfma16(af[0][0][s], qb[0][s], sT[0][0]);
        sT[0][1] = mfma16(af[0][0][s], qb[1][s], sT[0][1]);
        sT[1][0] = mfma16(af[0][1][s], qb[0][s], sT[1][0]);
        sT[1][1] = mfma16(af[0][1][s], qb[1][s], sT[1][1]);
      }
#pragma unroll
      for (int a = 0; a < 2; a++)
#pragma unroll
        for (int b = 0; b < 2; b++)
          sT[a][b] = mfma16(make8lo(aw[0][a], 0u), make8lo(bw[0][b], 0u), sT[a][b]);
#pragma unroll
      for (int b = 0; b < 2; b++) {
#pragma unroll
        for (int a = 0; a < 2; a++) {
          float p0 = EXP2(sT[a][b][0]);
          float p1 = EXP2(sT[a][b][1]);
          float p2 = EXP2(sT[a][b][2]);
          float p3 = EXP2(sT[a][b][3]);
          l_lane[b] += (p0 + p1) + (p2 + p3);
          uint2 w2; w2.x = cvtpk(p0, p1); w2.y = cvtpk(p2, p3);
          *(uint2*)&PsF[(wq * 32 + b * 16 + l15) * 72 + wk2 * 32 + a * 16 + quad * 4] = w2;
        }
      }
      bf16x8 pf0 = *reinterpret_cast<const bf16x8*>(&PsF[(wq * 32 + l15) * 72 + wk2 * 32 + quad * 8]);
      bf16x8 pf1 = *reinterpret_cast<const bf16x8*>(&PsF[(wq * 32 + 16 + l15) * 72 + wk2 * 32 + quad * 8]);
#pragma unroll
      for (int dt = 0; dt < 4; dt++) {
        od[dt][0] = mfma16(vf[0][dt], pf0, od[dt][0]);
        od[dt][1] = mfma16(vf[0][dt], pf1, od[dt][1]);
      }
    }

    __syncthreads();   // B2: all Ks/Vt reads done
    if (it < 31) {
      stageKV(it + 1);   // DMA overlaps half-1 compute
#pragma unroll
      for (int u = 0; u < 2; u++)
#pragma unroll
        for (int b = 0; b < 2; b++) {
          rhreg[u][b] = rhbase[(2 * it + 2 + u) * 64 + wq * 32 + b * 16 + l15];
          rwreg[u][b] = rwbase[(2 * it + 2 + u) * 64 + wk2 * 32 + b * 16 + l15];
        }
    }

    // ---------------- compute half 1 (t = 2it+1) ----------------
    {
      f32x4 sT[2][2];
#pragma unroll
      for (int a = 0; a < 2; a++)
#pragma unroll
        for (int b = 0; b < 2; b++) sT[a][b] = (f32x4){0.f, 0.f, 0.f, 0.f};
#pragma unroll
      for (int s = 0; s < 2; s++) {
        sT[0][0] = mfma16(af[1][0][s], qb[0][s], sT[0][0]);
        sT[0][1] = mfma16(af[1][0][s], qb[1][s], sT[0][1]);
        sT[1][0] = mfma16(af[1][1][s], qb[0][s], sT[1][0]);
        sT[1][1] = mfma16(af[1][1][s], qb[1][s], sT[1][1]);
      }
#pragma unroll
      for (int a = 0; a < 2; a++)
#pragma unroll
        for (int b = 0; b < 2; b++)
          sT[a][b] = mfma16(make8lo(aw[1][a], 0u), make8lo(bw[1][b], 0u), sT[a][b]);
#pragma unroll
      for (int b = 0; b < 2; b++) {
#pragma unroll
        for (int a = 0; a < 2; a++) {
          float p0 = EXP2(sT[a][b][0]);
          float p1 = EXP2(sT[a][b][1]);
          float p2 = EXP2(sT[a][b][2]);
          float p3 = EXP2(sT[a][b][3]);
          l_lane[b] += (p0 + p1) + (p2 + p3);
          uint2 w2; w2.x = cvtpk(p0, p1); w2.y = cvtpk(p2, p3);
          *(uint2*)&PsF[(wq * 32 + b * 16 + l15) * 72 + wk2 * 32 + a * 16 + quad * 4] = w2;
        }
      }
      bf16x8 pf0 = *reinterpret_cast<const bf16x8*>(&PsF[(wq * 32 + l15) * 72 + wk2 * 32 + quad * 8]);
      bf16x8 pf1 = *reinterpret_cast<const bf16x8*>(&PsF[(wq * 32 + 16 + l15) * 72 + wk2 * 32 + quad * 8]);
#pragma unroll
      for (int dt = 0; dt < 4; dt++) {
        od[dt][0] = mfma16(vf[1][dt], pf0, od[dt][0]);
        od[dt][1] = mfma16(vf[1][dt], pf1, od[dt][1]);
      }
    }
  }

  // --- combine l across quads, then across wk2 via LDS ---
#pragma unroll
  for (int b = 0; b < 2; b++) {
    l_lane[b] += __shfl_xor(l_lane[b], 16, 64);
    l_lane[b] += __shfl_xor(l_lane[b], 32, 64);
  }
  __syncthreads();   // all waves done with Ks/Vt/Ps before overlay
  if (lane < 16) {
#pragma unroll
    for (int b = 0; b < 2; b++)
      Lbuf[wk2 * 64 + wq * 32 + b * 16 + lane] = l_lane[b];
  }
#pragma unroll
  for (int dt = 0; dt < 4; dt++)
#pragma unroll
    for (int b = 0; b < 2; b++)
#pragma unroll
      for (int r = 0; r < 4; r++)
        o_buf[wk2 * 64 * 66 + (dt * 16 + quad * 4 + r) * 66 + (wq * 32 + b * 16 + l15)] =
            od[dt][b][r];
  __syncthreads();

  // --- cooperative epilogue: o = (part0+part1)/l, coalesced bf16 stores ---
  {
    const int q = tid >> 2, db = (tid & 3) * 16;
    const float linv = 1.0f / (Lbuf[q] + Lbuf[64 + q]);
    unsigned outd[8];
#pragma unroll
    for (int j = 0; j < 8; j++) {
      const int d0 = db + 2 * j;
      const float v0 = (o_buf[d0 * 66 + q] + o_buf[64 * 66 + d0 * 66 + q]) * linv;
      const float v1 = (o_buf[(d0 + 1) * 66 + q] + o_buf[64 * 66 + (d0 + 1) * 66 + q]) * linv;
      outd[j] = (unsigned)f2bf(v0) | ((unsigned)f2bf(v1) << 16);
    }
    uint4 s0 = make_uint4(outd[0], outd[1], outd[2], outd[3]);
    uint4 s1 = make_uint4(outd[4], outd[5], outd[6], outd[7]);
    *(uint4*)&ao_bf[(size_t)(q0 + q) * 768 + n * 64 + db]     = s0;
    *(uint4*)&ao_bf[(size_t)(q0 + q) * 768 + n * 64 + db + 8] = s1;
  }
}

// ---------------------------------------------------------------------------
// Output projection: 64x64 tiles, BK=64, grid (64,12)=768 = 3.0 blocks/CU.
// XOR-chunk-swizzled [64][64] LDS x2 (16 KB). Barriers 24. fp32 out.
// ---------------------------------------------------------------------------
__global__ __launch_bounds__(256) void proj_gemm(
    const ushort_t* __restrict__ ao_bf, const ushort_t* __restrict__ pw_bf,
    const float* __restrict__ pb, float* __restrict__ out) {
  __shared__ ushort_t As[64 * 64];
  __shared__ ushort_t Bs[64 * 64];
  const int m0 = blockIdx.x * 64, n0 = blockIdx.y * 64;
  const int tid = threadIdx.x;
  const int lane = tid & 63, wid = tid >> 6;
  const int l15 = lane & 15, quad = lane >> 4;
  const int wm = (wid & 1) * 32;
  const int wn = (wid >> 1) * 32;
  const int gr8 = lane >> 3;
  const int cl8 = (lane & 7) ^ (gr8 & 7);
  const int rsw = l15 & 7;

  f32x4 acc[2][2];
#pragma unroll
  for (int a = 0; a < 2; a++)
#pragma unroll
    for (int b = 0; b < 2; b++) acc[a][b] = (f32x4){0.f, 0.f, 0.f, 0.f};

  for (int kt = 0; kt < 12; kt++) {
    __syncthreads();
    const size_t kofs = (size_t)kt * 64 + cl8 * 8;
    glds16(&ao_bf[(size_t)(m0 + wid * 16 + gr8) * CIN + kofs],     &As[(wid * 16) * 64]);
    glds16(&ao_bf[(size_t)(m0 + wid * 16 + 8 + gr8) * CIN + kofs], &As[(wid * 16 + 8) * 64]);
    glds16(&pw_bf[(size_t)(n0 + wid * 16 + gr8) * CIN + kofs],     &Bs[(wid * 16) * 64]);
    glds16(&pw_bf[(size_t)(n0 + wid * 16 + 8 + gr8) * CIN + kofs], &Bs[(wid * 16 + 8) * 64]);
    __syncthreads();
    bf16x8 af[2][2], bfr[2][2];
#pragma unroll
    for (int mb = 0; mb < 2; mb++)
#pragma unroll
      for (int s = 0; s < 2; s++)
        af[mb][s] = *reinterpret_cast<const bf16x8*>(
            &As[(wm + mb * 16 + l15) * 64 + (((s * 4 + quad) ^ rsw) * 8)]);
#pragma unroll
    for (int nb = 0; nb < 2; nb++)
#pragma unroll
      for (int s = 0; s < 2; s++)
        bfr[nb][s] = *reinterpret_cast<const bf16x8*>(
            &Bs[(wn + nb * 16 + l15) * 64 + (((s * 4 + quad) ^ rsw) * 8)]);
#pragma unroll
    for (int mb = 0; mb < 2; mb++)
#pragma unroll
      for (int nb = 0; nb < 2; nb++)
#pragma unroll
        for (int s = 0; s < 2; s++)
          acc[mb][nb] = mfma16(af[mb][s], bfr[nb][s], acc[mb][nb]);
  }

#pragma unroll
  for (int mb = 0; mb < 2; mb++) {
#pragma unroll
    for (int nb = 0; nb < 2; nb++) {
      const int colg = n0 + wn + nb * 16 + l15;
      const float bias = pb[colg];
#pragma unroll
      for (int r = 0; r < 4; r++) {
        const int rowg = m0 + wm + mb * 16 + quad * 4 + r;
        out[(size_t)rowg * 768 + colg] = acc[mb][nb][r] + bias;
      }
    }
  }
}

// ---------------------------------------------------------------------------
extern "C" void kernel_launch(void* const* d_in, const int* in_sizes, int n_in,
                              void* d_out, int out_size, void* d_ws, size_t ws_size,
                              hipStream_t stream) {
  (void)in_sizes; (void)n_in; (void)out_size; (void)ws_size;
  const float* x   = (const float*)d_in[0];
  const float* wq  = (const float*)d_in[1];
  const float* bq  = (const float*)d_in[2];
  const float* wk  = (const float*)d_in[3];
  const float* bk  = (const float*)d_in[4];
  const float* wv  = (const float*)d_in[5];
  const float* bv  = (const float*)d_in[6];
  const float* rph = (const float*)d_in[7];
  const float* rpw = (const float*)d_in[8];
  const float* pw  = (const float*)d_in[9];
  const float* pb  = (const float*)d_in[10];
  float* out = (float*)d_out;

  char* ws = (char*)d_ws;
  size_t off = 0;
  auto alloc = [&](size_t bytes) -> char* {
    char* p = ws + off;
    off += (bytes + 255) & ~(size_t)255;
    return p;
  };
  ushort_t* x_bf   = (ushort_t*)alloc((size_t)HWP * CIN * 2);
  ushort_t* w_bf   = (ushort_t*)alloc((size_t)3 * NHD * HD * CIN * 2);
  ushort_t* pw_bf  = (ushort_t*)alloc((size_t)NHD * HD * CIN * 2);
  ushort_t* rph_bf = (ushort_t*)alloc((size_t)127 * HD * 2);
  ushort_t* rpw_bf = (ushort_t*)alloc((size_t)127 * HD * 2);
  float*    bias_all = (float*)alloc((size_t)3 * NHD * HD * 4);
  ushort_t* q_bf   = (ushort_t*)alloc((size_t)NHD * HWP * HD * 2);
  ushort_t* k_bf   = (ushort_t*)alloc((size_t)NHD * HWP * HD * 2);
  ushort_t* v_t    = (ushort_t*)alloc((size_t)NHD * HWP * HD * 2);
  ushort_t* rel_hT = (ushort_t*)alloc((size_t)NHD * HWP * 64 * 2);
  ushort_t* rel_w  = (ushort_t*)alloc((size_t)NHD * HWP * 64 * 2);
  ushort_t* ao_bf  = (ushort_t*)alloc((size_t)HWP * CIN * 2);

  convert_kernel<<<dim3(2048), dim3(256), 0, stream>>>(
      x, wq, bq, wk, bk, wv, bv, rph, rpw, pw,
      x_bf, w_bf, pw_bf, rph_bf, rpw_bf, bias_all);
  qkv_gemm<<<dim3(64, 18), dim3(256), 0, stream>>>(
      x_bf, w_bf, bias_all, q_bf, k_bf, v_t);
  rel_kernel<<<dim3(NHD * 64, 2), dim3(256), 0, stream>>>(
      q_bf, rph_bf, rpw_bf, rel_hT, rel_w);
  flash_kernel<<<dim3(NHD * 64), dim3(256), 0, stream>>>(
      q_bf, k_bf, v_t, rel_hT, rel_w, ao_bf);
  proj_gemm<<<dim3(64, 12), dim3(256), 0, stream>>>(ao_bf, pw_bf, pb, out);
}

// Round 15
// 206.471 us; speedup vs baseline: 2.1501x; 1.0073x over previous
//
#include <hip/hip_runtime.h>
#include <hip/hip_bf16.h>
#include <stdint.h>

// ---------------------------------------------------------------------------
// SAM encoder attention, MI355X/gfx950.
// convert(fp32->bf16, q pre-scaled by scale*log2e) -> qkv_gemm (64x128 tile,
// BK=64, grid 1152) -> rel_kernel -> flash v2.4 (early-B2 full DMA overlap,
// Ps ping-pong, l-via-MFMA) -> proj_gemm (64x64, BK=64, grid 768).
// MFMA 16x16x32 bf16; layouts per verified m89/m120 mappings:
//   A/B: m(n)=lane&15, k=quad*8+j ; C/D: col=lane&15, row=quad*4+reg.
// Lessons: K/V MUST stage through LDS (r6: 298us). Barrier amortization
// works (r8: 107.6->98.7). Bias-fold into MFMA slot-pair works (r10:
// 98.7->93.5). NEVER force occupancy via launch_bounds min-waves (r9/r12:
// VGPR collapse -> spills). GEMM dbuf neutral (r11); qkv BK=64 neutral (r14).
// r15 fix: r8 had placed B2 after half-0 compute, but frag reads for BOTH
// halves finish right after B1 -> move B2 up; stageKV now overlaps the WHOLE
// compute phase instead of half. + Ps0/Ps1 ping-pong (51.7KB < 53.3 -> still
// 3 blocks/CU) + l accumulated by MFMA ones-row (kills 32 adds/iter+shuffles).
// ---------------------------------------------------------------------------

typedef unsigned short ushort_t;
typedef __attribute__((ext_vector_type(8))) __bf16 bf16x8;
typedef __attribute__((ext_vector_type(4))) float f32x4;

#define NHD 12
#define HD 64
#define CIN 768
#define HWP 4096
#define QPRE 0.18033688f   /* 0.125 * log2(e) */

#if __has_builtin(__builtin_amdgcn_exp2f)
#define EXP2(x) __builtin_amdgcn_exp2f(x)
#else
#define EXP2(x) exp2f(x)
#endif

__device__ __forceinline__ ushort_t f2bf(float f) {
  union { float f; unsigned u; } v; v.f = f;
  unsigned r = (v.u + 0x7fffu + ((v.u >> 16) & 1u)) >> 16;  // RNE
  return (ushort_t)r;
}
__device__ __forceinline__ unsigned packbf(float a, float b) {
  unsigned ua = (__float_as_uint(a) + 0x8000u) >> 16;
  unsigned ub = (__float_as_uint(b) + 0x8000u) & 0xffff0000u;
  return ua | ub;
}
// HW packed f32x2 -> bf16x2 (v_cvt_pk_bf16_f32 on gfx950), lo=a hi=b
__device__ __forceinline__ unsigned cvtpk(float a, float b) {
  __hip_bfloat162 h = __float22bfloat162_rn(float2{a, b});
  unsigned u; __builtin_memcpy(&u, &h, 4); return u;
}
__device__ __forceinline__ f32x4 mfma16(bf16x8 a, bf16x8 b, f32x4 c) {
  return __builtin_amdgcn_mfma_f32_16x16x32_bf16(a, b, c, 0, 0, 0);
}
// bf16x8 with word0=(x), word1=(y), words 2-3 = 0 (zero slots are 0*0 in MFMA)
__device__ __forceinline__ bf16x8 make8lo(unsigned x, unsigned y) {
  union { uint4 u; bf16x8 v; } t;
  t.u = make_uint4(x, y, 0u, 0u);
  return t.v;
}
__device__ __forceinline__ bf16x8 ones8v() {
  union { uint4 u; bf16x8 v; } t;
  t.u = make_uint4(0x3F803F80u, 0x3F803F80u, 0x3F803F80u, 0x3F803F80u);
  return t.v;
}

// async global->LDS, 16B per lane. LDS dest = wave-uniform base + lane*16.
typedef const __attribute__((address_space(1))) unsigned int* gas_u32p;
typedef __attribute__((address_space(3))) unsigned int* las_u32p;
__device__ __forceinline__ void glds16(const ushort_t* g, ushort_t* l) {
  __builtin_amdgcn_global_load_lds((gas_u32p)g, (las_u32p)l, 16, 0, 0);
}

// ---------------------------------------------------------------------------
// fp32 -> bf16 conversions, vectorized (16B load / 8B store per lane).
// ---------------------------------------------------------------------------
__global__ void convert_kernel(const float* __restrict__ x,
                               const float* __restrict__ wq, const float* __restrict__ bq,
                               const float* __restrict__ wk, const float* __restrict__ bk,
                               const float* __restrict__ wv, const float* __restrict__ bv,
                               const float* __restrict__ rph, const float* __restrict__ rpw,
                               const float* __restrict__ pw,
                               ushort_t* __restrict__ x_bf, ushort_t* __restrict__ w_bf,
                               ushort_t* __restrict__ pw_bf, ushort_t* __restrict__ rph_bf,
                               ushort_t* __restrict__ rpw_bf, float* __restrict__ bias_all) {
  const int i = blockIdx.x * blockDim.x + threadIdx.x;
  const int stride = gridDim.x * blockDim.x;
  const int NX4 = (HWP * CIN) / 4;
  const int NW4 = (NHD * HD * CIN) / 4;
  const int NR4 = (127 * HD) / 4;
  for (int t = i; t < NX4; t += stride) {
    float4 a = ((const float4*)x)[t];
    uint2 o; o.x = packbf(a.x, a.y); o.y = packbf(a.z, a.w);
    ((uint2*)x_bf)[t] = o;
  }
  for (int t = i; t < NW4; t += stride) {
    float4 a = ((const float4*)wq)[t];
    float4 b = ((const float4*)wk)[t];
    float4 c = ((const float4*)wv)[t];
    float4 d = ((const float4*)pw)[t];
    uint2 o;
    o.x = packbf(a.x, a.y); o.y = packbf(a.z, a.w); ((uint2*)w_bf)[t] = o;
    o.x = packbf(b.x, b.y); o.y = packbf(b.z, b.w); ((uint2*)w_bf)[NW4 + t] = o;
    o.x = packbf(c.x, c.y); o.y = packbf(c.z, c.w); ((uint2*)w_bf)[2 * NW4 + t] = o;
    o.x = packbf(d.x, d.y); o.y = packbf(d.z, d.w); ((uint2*)pw_bf)[t] = o;
  }
  for (int t = i; t < NR4; t += stride) {
    float4 a = ((const float4*)rph)[t];
    float4 b = ((const float4*)rpw)[t];
    uint2 o;
    o.x = packbf(a.x, a.y); o.y = packbf(a.z, a.w); ((uint2*)rph_bf)[t] = o;
    o.x = packbf(b.x, b.y); o.y = packbf(b.z, b.w); ((uint2*)rpw_bf)[t] = o;
  }
  for (int t = i; t < NHD * HD; t += stride) {
    bias_all[t]        = bq[t];
    bias_all[768 + t]  = bk[t];
    bias_all[1536 + t] = bv[t];
  }
}

// ---------------------------------------------------------------------------
// QKV GEMM (r14): 64x128 tile, 256 threads, BK=64, grid (64,18)=1152.
// glds staging into XOR-chunk-swizzled [64][64]/[128][64] LDS.
// q pre-scaled by QPRE; v packed 8B to [n][d][p].
// ---------------------------------------------------------------------------
__global__ __launch_bounds__(256) void qkv_gemm(
    const ushort_t* __restrict__ x_bf, const ushort_t* __restrict__ w_bf,
    const float* __restrict__ bias_all,
    ushort_t* __restrict__ q_bf, ushort_t* __restrict__ k_bf, ushort_t* __restrict__ v_t) {
  __shared__ ushort_t As[64 * 64];    // 8 KB
  __shared__ ushort_t Bs[128 * 64];   // 16 KB
  const int m0 = blockIdx.x * 64, n0 = blockIdx.y * 128;
  const int tid = threadIdx.x;
  const int lane = tid & 63, wid = tid >> 6;
  const int l15 = lane & 15, quad = lane >> 4;
  const int wm = (wid & 1) * 32;
  const int wn = (wid >> 1) * 64;
  const int gr8 = lane >> 3;
  const int cl8 = (lane & 7) ^ (gr8 & 7);
  const int rsw = l15 & 7;

  f32x4 acc[2][4];
#pragma unroll
  for (int a = 0; a < 2; a++)
#pragma unroll
    for (int b = 0; b < 4; b++) acc[a][b] = (f32x4){0.f, 0.f, 0.f, 0.f};

  for (int kt = 0; kt < 12; kt++) {
    __syncthreads();
    const size_t kofs = (size_t)kt * 64 + cl8 * 8;
    glds16(&x_bf[(size_t)(m0 + wid * 16 + gr8) * CIN + kofs],     &As[(wid * 16) * 64]);
    glds16(&x_bf[(size_t)(m0 + wid * 16 + 8 + gr8) * CIN + kofs], &As[(wid * 16 + 8) * 64]);
    glds16(&w_bf[(size_t)(n0 + wid * 32 + gr8) * CIN + kofs],      &Bs[(wid * 32) * 64]);
    glds16(&w_bf[(size_t)(n0 + wid * 32 + 8 + gr8) * CIN + kofs],  &Bs[(wid * 32 + 8) * 64]);
    glds16(&w_bf[(size_t)(n0 + wid * 32 + 16 + gr8) * CIN + kofs], &Bs[(wid * 32 + 16) * 64]);
    glds16(&w_bf[(size_t)(n0 + wid * 32 + 24 + gr8) * CIN + kofs], &Bs[(wid * 32 + 24) * 64]);
    __syncthreads();
    bf16x8 af[2][2], bfr[4][2];
#pragma unroll
    for (int mb = 0; mb < 2; mb++)
#pragma unroll
      for (int s = 0; s < 2; s++)
        af[mb][s] = *reinterpret_cast<const bf16x8*>(
            &As[(wm + mb * 16 + l15) * 64 + (((s * 4 + quad) ^ rsw) * 8)]);
#pragma unroll
    for (int nb = 0; nb < 4; nb++)
#pragma unroll
      for (int s = 0; s < 2; s++)
        bfr[nb][s] = *reinterpret_cast<const bf16x8*>(
            &Bs[(wn + nb * 16 + l15) * 64 + (((s * 4 + quad) ^ rsw) * 8)]);
#pragma unroll
    for (int mb = 0; mb < 2; mb++)
#pragma unroll
      for (int nb = 0; nb < 4; nb++)
#pragma unroll
        for (int s = 0; s < 2; s++)
          acc[mb][nb] = mfma16(af[mb][s], bfr[nb][s], acc[mb][nb]);
  }

#pragma unroll
  for (int mb = 0; mb < 2; mb++) {
#pragma unroll
    for (int nb = 0; nb < 4; nb++) {
      const int colg = n0 + wn + nb * 16 + l15;
      const float bias = bias_all[colg];
      if (colg >= 1536) {
        const int j = colg - 1536;
        uint2 wv2;
        wv2.x = packbf(acc[mb][nb][0] + bias, acc[mb][nb][1] + bias);
        wv2.y = packbf(acc[mb][nb][2] + bias, acc[mb][nb][3] + bias);
        *(uint2*)&v_t[(size_t)j * HWP + m0 + wm + mb * 16 + quad * 4] = wv2;
      } else {
#pragma unroll
        for (int r = 0; r < 4; r++) {
          const int rowg = m0 + wm + mb * 16 + quad * 4 + r;
          const float val = acc[mb][nb][r] + bias;
          if (colg < 768) {
            q_bf[(((size_t)(colg >> 6)) * HWP + rowg) * HD + (colg & 63)] = f2bf(val * QPRE);
          } else {
            const int j = colg - 768;
            k_bf[(((size_t)(j >> 6)) * HWP + rowg) * HD + (j & 63)] = f2bf(val);
          }
        }
      }
    }
  }
}

// ---------------------------------------------------------------------------
// rel tables. mode 0 -> rel_hT[n][h][t][w]; mode 1 -> rel_w[n][p][w2].
// Outputs *8 => rel * log2(e)  (q_bf pre-scaled by QPRE).
// ---------------------------------------------------------------------------
__global__ __launch_bounds__(256) void rel_kernel(
    const ushort_t* __restrict__ q_bf, const ushort_t* __restrict__ rph_bf,
    const ushort_t* __restrict__ rpw_bf,
    ushort_t* __restrict__ rel_hT, ushort_t* __restrict__ rel_w) {
  const int mode = blockIdx.y;
  const ushort_t* __restrict__ rp_bf = mode ? rpw_bf : rph_bf;
  const int bx = blockIdx.x;
  const int n = bx >> 6, hw = bx & 63;
  const int tid = threadIdx.x;
  const int lane = tid & 63, wid = tid >> 6;
  const int l15 = lane & 15, quad = lane >> 4;

  __shared__ ushort_t Qs[64][72];
  __shared__ ushort_t Rs[64][72];

  const int r0 = tid >> 3, c8 = (tid & 7) * 8;
#pragma unroll
  for (int h = 0; h < 2; h++) {
    const int r = r0 + h * 32;
    const int p = (mode == 0) ? (hw * 64 + r) : (r * 64 + hw);
    *(uint4*)&Qs[r][c8] = *(const uint4*)&q_bf[((size_t)n * HWP + p) * HD + c8];
    *(uint4*)&Rs[r][c8] = *(const uint4*)&rp_bf[(63 + hw - r) * HD + c8];
  }
  __syncthreads();

  bf16x8 a0 = *reinterpret_cast<const bf16x8*>(&Qs[wid * 16 + l15][quad * 8]);
  bf16x8 a1 = *reinterpret_cast<const bf16x8*>(&Qs[wid * 16 + l15][32 + quad * 8]);
#pragma unroll
  for (int nb = 0; nb < 4; nb++) {
    bf16x8 b0 = *reinterpret_cast<const bf16x8*>(&Rs[nb * 16 + l15][quad * 8]);
    bf16x8 b1 = *reinterpret_cast<const bf16x8*>(&Rs[nb * 16 + l15][32 + quad * 8]);
    f32x4 c = (f32x4){0.f, 0.f, 0.f, 0.f};
    c = mfma16(a0, b0, c);
    c = mfma16(a1, b1, c);
    const int col = nb * 16 + l15;
    if (mode == 0) {
      uint2 o;
      o.x = packbf(c[0] * 8.0f, c[1] * 8.0f);
      o.y = packbf(c[2] * 8.0f, c[3] * 8.0f);
      *(uint2*)&rel_hT[(((size_t)(n * 64 + hw) * 64) + col) * 64 + wid * 16 + quad * 4] = o;
    } else {
#pragma unroll
      for (int r = 0; r < 4; r++) {
        const int lr = wid * 16 + quad * 4 + r;
        const int p2 = lr * 64 + hw;
        rel_w[((size_t)n * HWP + p2) * 64 + col] = f2bf(c[r] * 8.0f);
      }
    }
  }
}

// ---------------------------------------------------------------------------
// Flash attention v2.4. Block = (head n, q-row qt); 4 waves 2x2 (wq, wk2);
// 128-key double-tile per barrier pair. Changes vs r10/r14 (92.9 us):
//  * B2 moved up to right after the (register) fragment reads -> stageKV
//    DMA for it+1 overlaps the ENTIRE compute phase (was: only half 1).
//  * Ps0/Ps1 ping-pong: both halves' S->exp->write complete before any pf
//    read (write->read slack ~150cyc). LDS 51.7KB -> still 3 blocks/CU.
//  * l accumulated via MFMA ones-row on pf (C col=l15 == q mapping) ->
//    removes 32 VALU adds/iter + cross-quad shuffles; l sums bf16 P (err
//    ~3e-5 relative, negligible).
// Bias folded into MFMA slot-pairing; no-max exp2 softmax.
// ---------------------------------------------------------------------------
__global__ __launch_bounds__(256, 3) void flash_kernel(
    const ushort_t* __restrict__ q_bf, const ushort_t* __restrict__ k_bf,
    const ushort_t* __restrict__ v_t, const ushort_t* __restrict__ rel_hT,
    const ushort_t* __restrict__ rel_w, ushort_t* __restrict__ ao_bf) {
  const int bx = blockIdx.x;
  const int n = bx >> 6, qt = bx & 63;
  const int q0 = qt * 64;
  const int tid = threadIdx.x;
  const int lane = tid & 63, wid = tid >> 6;
  const int l15 = lane & 15, quad = lane >> 4;
  const int wq = wid & 1, wk2 = wid >> 1;

  // LDS: Ks0@0, Ks1@8192, Vt0@16384, Vt1@24576 (each [64][64] bf16 = 8KB),
  // Ps0/Qs@32768 [64][72] (9216), Ps1@41984 [64][72] (9216),
  // Lbuf@51200 [2][64] f32 (512). Total 51712 (<53.3KB -> 3 blocks/CU).
  // o_buf [2][64][66] f32 (33792) overlays [0,33792) in the epilogue.
  __shared__ __align__(16) char smem[51712];
  ushort_t* Ks[2] = {(ushort_t*)smem, (ushort_t*)(smem + 8192)};
  ushort_t* Vt[2] = {(ushort_t*)(smem + 16384), (ushort_t*)(smem + 24576)};
  ushort_t* Ps[2] = {(ushort_t*)(smem + 32768), (ushort_t*)(smem + 41984)};
  float* Lbuf  = (float*)(smem + 51200);
  float* o_buf = (float*)smem;

  const int r0 = tid >> 3, c8 = (tid & 7) * 8;
#pragma unroll
  for (int h = 0; h < 2; h++) {
    const int r = r0 + h * 32;
    *(uint4*)&Ps[0][r * 72 + c8] = *(const uint4*)&q_bf[((size_t)n * HWP + q0 + r) * HD + c8];
  }
  __syncthreads();

  bf16x8 qb[2][2];
#pragma unroll
  for (int b = 0; b < 2; b++)
#pragma unroll
    for (int s = 0; s < 2; s++)
      qb[b][s] = *reinterpret_cast<const bf16x8*>(&Ps[0][(wq * 32 + b * 16 + l15) * 72 + s * 32 + quad * 8]);
  // First Ps[0] write happens after B1 of it=0, which orders it against these
  // qb reads across all waves (barrier semantics).

  const int gr8 = lane >> 3;
  const int cl8 = (lane & 7) ^ ((lane >> 3) & 7);  // swizzled src col group
  const int rsw = l15 & 7;                         // read-side swizzle key

  // stages key tiles 2*it2 (buf 0) and 2*it2+1 (buf 1)
  auto stageKV = [&](int it2) {
#pragma unroll
    for (int u = 0; u < 2; u++) {
      const int tt = 2 * it2 + u;
      const size_t kbase = ((size_t)n * HWP + (size_t)tt * 64 + gr8) * HD + cl8 * 8;
#pragma unroll
      for (int i = 0; i < 2; i++) {
        const int R0 = wid * 16 + i * 8;
        glds16(&k_bf[kbase + (size_t)R0 * HD], &Ks[u][R0 * 64]);
      }
      const size_t vbase = ((size_t)n * HD + gr8) * HWP + (size_t)tt * 64 + cl8 * 8;
#pragma unroll
      for (int i = 0; i < 2; i++) {
        const int R0 = wid * 16 + i * 8;
        glds16(&v_t[vbase + (size_t)R0 * HWP], &Vt[u][R0 * 64]);
      }
    }
  };

  stageKV(0);

  // rh (per-q) and rw (per-key) prefetch, u16, coalesced:
  const ushort_t* rhbase = rel_hT + (((size_t)n * 64 + qt) << 12);
  const ushort_t* rwbase = rel_w + (((size_t)n * HWP + q0) << 6);
  ushort_t rhreg[2][2], rwreg[2][2];
#pragma unroll
  for (int u = 0; u < 2; u++) {
#pragma unroll
    for (int b = 0; b < 2; b++) {
      rhreg[u][b] = rhbase[u * 64 + wq * 32 + b * 16 + l15];
      rwreg[u][b] = rwbase[u * 64 + wk2 * 32 + b * 16 + l15];
    }
  }

  f32x4 od[4][2];
#pragma unroll
  for (int dt = 0; dt < 4; dt++)
#pragma unroll
    for (int b = 0; b < 2; b++) od[dt][b] = (f32x4){0.f, 0.f, 0.f, 0.f};
  f32x4 odl[2] = {(f32x4){0.f, 0.f, 0.f, 0.f}, (f32x4){0.f, 0.f, 0.f, 0.f}};

  const bool isq0 = (quad == 0);
  const bf16x8 ones8 = ones8v();

  for (int it = 0; it < 32; it++) {
    __syncthreads();   // B1: DMA(it) complete everywhere (vmcnt drained)

    // --- fragment reads for BOTH halves (registers) ---
    bf16x8 af[2][2][2], vf[2][4];
#pragma unroll
    for (int u = 0; u < 2; u++) {
#pragma unroll
      for (int a = 0; a < 2; a++)
#pragma unroll
        for (int s = 0; s < 2; s++)
          af[u][a][s] = *reinterpret_cast<const bf16x8*>(
              &Ks[u][(wk2 * 32 + a * 16 + l15) * 64 + ((s * 4 + quad) ^ rsw) * 8]);
#pragma unroll
      for (int dt = 0; dt < 4; dt++)
        vf[u][dt] = *reinterpret_cast<const bf16x8*>(
            &Vt[u][(dt * 16 + l15) * 64 + ((wk2 * 4 + quad) ^ rsw) * 8]);
    }

    // --- bias MFMA operand words (A: {1.0, rw}; B: {rh, 1.0}; lanes q>0: 0) ---
    unsigned aw[2][2], bw[2][2];
#pragma unroll
    for (int u = 0; u < 2; u++)
#pragma unroll
      for (int i = 0; i < 2; i++) {
        aw[u][i] = isq0 ? (((unsigned)rwreg[u][i] << 16) | 0x3F80u) : 0u;
        bw[u][i] = isq0 ? (0x3F800000u | (unsigned)rhreg[u][i]) : 0u;
      }

    __syncthreads();   // B2: all Ks/Vt consumed into registers
    if (it < 31) {
      stageKV(it + 1);   // DMA overlaps the ENTIRE compute phase below
#pragma unroll
      for (int u = 0; u < 2; u++)
#pragma unroll
        for (int b = 0; b < 2; b++) {
          rhreg[u][b] = rhbase[(2 * it + 2 + u) * 64 + wq * 32 + b * 16 + l15];
          rwreg[u][b] = rwbase[(2 * it + 2 + u) * 64 + wk2 * 32 + b * 16 + l15];
        }
    }

    // --- S/exp/write for both halves (Ps ping-pong, wave-local) ---
#pragma unroll
    for (int u = 0; u < 2; u++) {
      f32x4 sT[2][2];
#pragma unroll
      for (int a = 0; a < 2; a++)
#pragma unroll
        for (int b = 0; b < 2; b++) sT[a][b] = (f32x4){0.f, 0.f, 0.f, 0.f};
#pragma unroll
      for (int s = 0; s < 2; s++) {
        sT[0][0] = mfma16(af[u][0][s], qb[0][s], sT[0][0]);
        sT[0][1] = mfma16(af[u][0][s], qb[1][s], sT[0][1]);
        sT[1][0] = mfma16(af[u][1][s], qb[0][s], sT[1][0]);
        sT[1][1] = mfma16(af[u][1][s], qb[1][s], sT[1][1]);
      }
#pragma unroll
      for (int a = 0; a < 2; a++)
#pragma unroll
        for (int b = 0; b < 2; b++)
          sT[a][b] = mfma16(make8lo(aw[u][a], 0u), make8lo(bw[u][b], 0u), sT[a][b]);
#pragma unroll
      for (int b = 0; b < 2; b++) {
#pragma unroll
        for (int a = 0; a < 2; a++) {
          float p0 = EXP2(sT[a][b][0]);
          float p1 = EXP2(sT[a][b][1]);
          float p2 = EXP2(sT[a][b][2]);
          float p3 = EXP2(sT[a][b][3]);
          uint2 w2; w2.x = cvtpk(p0, p1); w2.y = cvtpk(p2, p3);
          *(uint2*)&Ps[u][(wq * 32 + b * 16 + l15) * 72 + wk2 * 32 + a * 16 + quad * 4] = w2;
        }
      }
    }

    // --- PV + l for both halves (pf reads have full write->read slack) ---
#pragma unroll
    for (int u = 0; u < 2; u++) {
      bf16x8 pf0 = *reinterpret_cast<const bf16x8*>(&Ps[u][(wq * 32 + l15) * 72 + wk2 * 32 + quad * 8]);
      bf16x8 pf1 = *reinterpret_cast<const bf16x8*>(&Ps[u][(wq * 32 + 16 + l15) * 72 + wk2 * 32 + quad * 8]);
#pragma unroll
      for (int dt = 0; dt < 4; dt++) {
        od[dt][0] = mfma16(vf[u][dt], pf0, od[dt][0]);
        od[dt][1] = mfma16(vf[u][dt], pf1, od[dt][1]);
      }
      odl[0] = mfma16(ones8, pf0, odl[0]);
      odl[1] = mfma16(ones8, pf1, odl[1]);
    }
  }

  // --- l: already summed over quads by the ones-MFMA (col=l15 == q) ---
  float l_lane[2] = {odl[0][0], odl[1][0]};
  __syncthreads();   // all waves done with Ks/Vt/Ps before overlay
  if (lane < 16) {
#pragma unroll
    for (int b = 0; b < 2; b++)
      Lbuf[wk2 * 64 + wq * 32 + b * 16 + lane] = l_lane[b];
  }
#pragma unroll
  for (int dt = 0; dt < 4; dt++)
#pragma unroll
    for (int b = 0; b < 2; b++)
#pragma unroll
      for (int r = 0; r < 4; r++)
        o_buf[wk2 * 64 * 66 + (dt * 16 + quad * 4 + r) * 66 + (wq * 32 + b * 16 + l15)] =
            od[dt][b][r];
  __syncthreads();

  // --- cooperative epilogue: o = (part0+part1)/l, coalesced bf16 stores ---
  {
    const int q = tid >> 2, db = (tid & 3) * 16;
    const float linv = 1.0f / (Lbuf[q] + Lbuf[64 + q]);
    unsigned outd[8];
#pragma unroll
    for (int j = 0; j < 8; j++) {
      const int d0 = db + 2 * j;
      const float v0 = (o_buf[d0 * 66 + q] + o_buf[64 * 66 + d0 * 66 + q]) * linv;
      const float v1 = (o_buf[(d0 + 1) * 66 + q] + o_buf[64 * 66 + (d0 + 1) * 66 + q]) * linv;
      outd[j] = (unsigned)f2bf(v0) | ((unsigned)f2bf(v1) << 16);
    }
    uint4 s0 = make_uint4(outd[0], outd[1], outd[2], outd[3]);
    uint4 s1 = make_uint4(outd[4], outd[5], outd[6], outd[7]);
    *(uint4*)&ao_bf[(size_t)(q0 + q) * 768 + n * 64 + db]     = s0;
    *(uint4*)&ao_bf[(size_t)(q0 + q) * 768 + n * 64 + db + 8] = s1;
  }
}

// ---------------------------------------------------------------------------
// Output projection (r14): 64x64 tiles, BK=64, grid (64,12)=768. fp32 out.
// ---------------------------------------------------------------------------
__global__ __launch_bounds__(256) void proj_gemm(
    const ushort_t* __restrict__ ao_bf, const ushort_t* __restrict__ pw_bf,
    const float* __restrict__ pb, float* __restrict__ out) {
  __shared__ ushort_t As[64 * 64];
  __shared__ ushort_t Bs[64 * 64];
  const int m0 = blockIdx.x * 64, n0 = blockIdx.y * 64;
  const int tid = threadIdx.x;
  const int lane = tid & 63, wid = tid >> 6;
  const int l15 = lane & 15, quad = lane >> 4;
  const int wm = (wid & 1) * 32;
  const int wn = (wid >> 1) * 32;
  const int gr8 = lane >> 3;
  const int cl8 = (lane & 7) ^ (gr8 & 7);
  const int rsw = l15 & 7;

  f32x4 acc[2][2];
#pragma unroll
  for (int a = 0; a < 2; a++)
#pragma unroll
    for (int b = 0; b < 2; b++) acc[a][b] = (f32x4){0.f, 0.f, 0.f, 0.f};

  for (int kt = 0; kt < 12; kt++) {
    __syncthreads();
    const size_t kofs = (size_t)kt * 64 + cl8 * 8;
    glds16(&ao_bf[(size_t)(m0 + wid * 16 + gr8) * CIN + kofs],     &As[(wid * 16) * 64]);
    glds16(&ao_bf[(size_t)(m0 + wid * 16 + 8 + gr8) * CIN + kofs], &As[(wid * 16 + 8) * 64]);
    glds16(&pw_bf[(size_t)(n0 + wid * 16 + gr8) * CIN + kofs],     &Bs[(wid * 16) * 64]);
    glds16(&pw_bf[(size_t)(n0 + wid * 16 + 8 + gr8) * CIN + kofs], &Bs[(wid * 16 + 8) * 64]);
    __syncthreads();
    bf16x8 af[2][2], bfr[2][2];
#pragma unroll
    for (int mb = 0; mb < 2; mb++)
#pragma unroll
      for (int s = 0; s < 2; s++)
        af[mb][s] = *reinterpret_cast<const bf16x8*>(
            &As[(wm + mb * 16 + l15) * 64 + (((s * 4 + quad) ^ rsw) * 8)]);
#pragma unroll
    for (int nb = 0; nb < 2; nb++)
#pragma unroll
      for (int s = 0; s < 2; s++)
        bfr[nb][s] = *reinterpret_cast<const bf16x8*>(
            &Bs[(wn + nb * 16 + l15) * 64 + (((s * 4 + quad) ^ rsw) * 8)]);
#pragma unroll
    for (int mb = 0; mb < 2; mb++)
#pragma unroll
      for (int nb = 0; nb < 2; nb++)
#pragma unroll
        for (int s = 0; s < 2; s++)
          acc[mb][nb] = mfma16(af[mb][s], bfr[nb][s], acc[mb][nb]);
  }

#pragma unroll
  for (int mb = 0; mb < 2; mb++) {
#pragma unroll
    for (int nb = 0; nb < 2; nb++) {
      const int colg = n0 + wn + nb * 16 + l15;
      const float bias = pb[colg];
#pragma unroll
      for (int r = 0; r < 4; r++) {
        const int rowg = m0 + wm + mb * 16 + quad * 4 + r;
        out[(size_t)rowg * 768 + colg] = acc[mb][nb][r] + bias;
      }
    }
  }
}

// ---------------------------------------------------------------------------
extern "C" void kernel_launch(void* const* d_in, const int* in_sizes, int n_in,
                              void* d_out, int out_size, void* d_ws, size_t ws_size,
                              hipStream_t stream) {
  (void)in_sizes; (void)n_in; (void)out_size; (void)ws_size;
  const float* x   = (const float*)d_in[0];
  const float* wq  = (const float*)d_in[1];
  const float* bq  = (const float*)d_in[2];
  const float* wk  = (const float*)d_in[3];
  const float* bk  = (const float*)d_in[4];
  const float* wv  = (const float*)d_in[5];
  const float* bv  = (const float*)d_in[6];
  const float* rph = (const float*)d_in[7];
  const float* rpw = (const float*)d_in[8];
  const float* pw  = (const float*)d_in[9];
  const float* pb  = (const float*)d_in[10];
  float* out = (float*)d_out;

  char* ws = (char*)d_ws;
  size_t off = 0;
  auto alloc = [&](size_t bytes) -> char* {
    char* p = ws + off;
    off += (bytes + 255) & ~(size_t)255;
    return p;
  };
  ushort_t* x_bf   = (ushort_t*)alloc((size_t)HWP * CIN * 2);
  ushort_t* w_bf   = (ushort_t*)alloc((size_t)3 * NHD * HD * CIN * 2);
  ushort_t* pw_bf  = (ushort_t*)alloc((size_t)NHD * HD * CIN * 2);
  ushort_t* rph_bf = (ushort_t*)alloc((size_t)127 * HD * 2);
  ushort_t* rpw_bf = (ushort_t*)alloc((size_t)127 * HD * 2);
  float*    bias_all = (float*)alloc((size_t)3 * NHD * HD * 4);
  ushort_t* q_bf   = (ushort_t*)alloc((size_t)NHD * HWP * HD * 2);
  ushort_t* k_bf   = (ushort_t*)alloc((size_t)NHD * HWP * HD * 2);
  ushort_t* v_t    = (ushort_t*)alloc((size_t)NHD * HWP * HD * 2);
  ushort_t* rel_hT = (ushort_t*)alloc((size_t)NHD * HWP * 64 * 2);
  ushort_t* rel_w  = (ushort_t*)alloc((size_t)NHD * HWP * 64 * 2);
  ushort_t* ao_bf  = (ushort_t*)alloc((size_t)HWP * CIN * 2);

  convert_kernel<<<dim3(2048), dim3(256), 0, stream>>>(
      x, wq, bq, wk, bk, wv, bv, rph, rpw, pw,
      x_bf, w_bf, pw_bf, rph_bf, rpw_bf, bias_all);
  qkv_gemm<<<dim3(64, 18), dim3(256), 0, stream>>>(
      x_bf, w_bf, bias_all, q_bf, k_bf, v_t);
  rel_kernel<<<dim3(NHD * 64, 2), dim3(256), 0, stream>>>(
      q_bf, rph_bf, rpw_bf, rel_hT, rel_w);
  flash_kernel<<<dim3(NHD * 64), dim3(256), 0, stream>>>(
      q_bf, k_bf, v_t, rel_hT, rel_w, ao_bf);
  proj_gemm<<<dim3(64, 12), dim3(256), 0, stream>>>(ao_bf, pw_bf, pb, out);
}